// Round 1
// 2218.492 us; speedup vs baseline: 2.8821x; 2.8821x over previous
//
#include <hip/hip_runtime.h>

typedef __attribute__((ext_vector_type(8))) short bf16x8;
typedef __attribute__((ext_vector_type(4))) float f32x4;
typedef __attribute__((ext_vector_type(4))) unsigned short u16x4;

#define Bdim 256
#define Sdim 141
#define Vdim 1000
#define Edim 256
#define Hdim 512
#define G4H  2048

__device__ __forceinline__ float bf2f(unsigned short u) {
    union { unsigned int i; float f; } x; x.i = ((unsigned int)u) << 16; return x.f;
}
__device__ __forceinline__ unsigned short f2bf(float f) {
    union { float f; unsigned int i; } x; x.f = f;
    unsigned int i = x.i;
    return (unsigned short)((i + 0x7FFFu + ((i >> 16) & 1u)) >> 16);  // RNE
}
__device__ __forceinline__ float sigmoid_f(float x) { return 1.f / (1.f + __expf(-x)); }
__device__ __forceinline__ float tanh_f(float x)    { return 1.f - 2.f / (__expf(2.f * x) + 1.f); }

__device__ __forceinline__ bf16x8 cvt8(const float* p) {
    const float4 v0 = ((const float4*)p)[0];
    const float4 v1 = ((const float4*)p)[1];
    bf16x8 r;
    r[0] = (short)f2bf(v0.x); r[1] = (short)f2bf(v0.y);
    r[2] = (short)f2bf(v0.z); r[3] = (short)f2bf(v0.w);
    r[4] = (short)f2bf(v1.x); r[5] = (short)f2bf(v1.y);
    r[6] = (short)f2bf(v1.z); r[7] = (short)f2bf(v1.w);
    return r;
}

// ---------------------------------------------------------------------------
// Bulk fp32 -> bf16 (RNE), vectorized x4.
// ---------------------------------------------------------------------------
__global__ __launch_bounds__(256) void f32_to_bf16_4(
    const float4* __restrict__ src, u16x4* __restrict__ dst, int n4)
{
    const int i = blockIdx.x * 256 + threadIdx.x;
    if (i < n4) {
        const float4 v = src[i];
        u16x4 r;
        r[0] = f2bf(v.x); r[1] = f2bf(v.y); r[2] = f2bf(v.z); r[3] = f2bf(v.w);
        dst[i] = r;
    }
}

// ---------------------------------------------------------------------------
// C = A * B^T (+bias), fp32 inputs converted inline to bf16 for MFMA.
// Tile 128x64, 4 waves. Layouts verified (m89/m92).
// ---------------------------------------------------------------------------
template <bool BF16OUT>
__global__ __launch_bounds__(256) void gemm_bt_f32in(
    const float* __restrict__ A, int lda, int M,
    const float* __restrict__ Bw, int ldb,
    void* __restrict__ Cv, int ldc,
    const float* __restrict__ bias0,
    const float* __restrict__ bias1,
    int K)
{
    const int m0 = blockIdx.x * 128;
    const int n0 = blockIdx.y * 64;
    const int w    = threadIdx.x >> 6;
    const int l    = threadIdx.x & 63;
    const int lr   = l & 15;
    const int quad = l >> 4;

    int ra0 = m0 + w * 32 + lr;
    int ra1 = ra0 + 16;
    ra0 = ra0 < M ? ra0 : M - 1;
    ra1 = ra1 < M ? ra1 : M - 1;
    const float* pa0 = A + (size_t)ra0 * lda + quad * 8;
    const float* pa1 = A + (size_t)ra1 * lda + quad * 8;
    const float* pb[4];
#pragma unroll
    for (int nj = 0; nj < 4; ++nj)
        pb[nj] = Bw + (size_t)(n0 + nj * 16 + lr) * ldb + quad * 8;

    f32x4 acc[2][4];
#pragma unroll
    for (int mi = 0; mi < 2; ++mi)
#pragma unroll
        for (int nj = 0; nj < 4; ++nj)
            acc[mi][nj] = (f32x4){0.f, 0.f, 0.f, 0.f};

    for (int k = 0; k < K; k += 32) {
        bf16x8 a0 = cvt8(pa0 + k);
        bf16x8 a1 = cvt8(pa1 + k);
#pragma unroll
        for (int nj = 0; nj < 4; ++nj) {
            bf16x8 bb = cvt8(pb[nj] + k);
            acc[0][nj] = __builtin_amdgcn_mfma_f32_16x16x32_bf16(a0, bb, acc[0][nj], 0, 0, 0);
            acc[1][nj] = __builtin_amdgcn_mfma_f32_16x16x32_bf16(a1, bb, acc[1][nj], 0, 0, 0);
        }
    }

#pragma unroll
    for (int nj = 0; nj < 4; ++nj) {
        const int col = n0 + nj * 16 + lr;
        float bv = 0.f;
        if (bias0) bv += bias0[col];
        if (bias1) bv += bias1[col];
#pragma unroll
        for (int mi = 0; mi < 2; ++mi) {
            const int row = m0 + w * 32 + mi * 16 + quad * 4;
#pragma unroll
            for (int r = 0; r < 4; ++r) {
                if (row + r < M) {
                    const float v = acc[mi][nj][r] + bv;
                    if (BF16OUT)
                        ((unsigned short*)Cv)[(size_t)(row + r) * ldc + col] = f2bf(v);
                    else
                        ((float*)Cv)[(size_t)(row + r) * ldc + col] = v;
                }
            }
        }
    }
}

// ---------------------------------------------------------------------------
// Per-batch-tile grid barrier: 64 blocks (same bi) rendezvous. Monotonic
// counters (NO resets -> no reset race): group g done in epoch `target` when
// its counter reaches target*16; tile root done when it reaches target*4;
// then epoch[bi] = target. Bounded spin: a logic bug gives a finite wrong
// answer, not a hang.
//
// Memory-order rationale (gfx950, per-XCD L2 NOT cross-coherent):
//  - ONE agent-release fence (buffer_wbl2) before the arrival RMW flushes
//    this block's h stores to the coherent point (L3). In-order VMEM issue
//    + the fence's s_waitcnt orders the RMW after writeback completion.
//  - All barrier atomics RELAXED: agent-scope atomics execute at the
//    coherent point regardless of ordering; ACQ_REL/ACQUIRE would add a
//    buffer_wbl2/buffer_inv PER OPERATION — the acquire-poll variant
//    invalidated the whole XCD L2 every poll iteration (the prior 43us/step).
//  - NO per-step acquire invalidate: h_t lives at virgin addresses each
//    step (hs + t*B*H), so no consumer L1/L2 can hold a stale copy; a
//    workgroup-scope fence provides compiler ordering only (s_waitcnt).
//    Hedge: if the spin stalls (>256 polls), re-issue an agent-acquire
//    fence — free on the normal path, bounds staleness if the relaxed
//    poll ever fails to bypass a stale cache.
// ---------------------------------------------------------------------------
__device__ __forceinline__ void tile_sync(unsigned* bar, int bi, int blk, unsigned target) {
    __syncthreads();
    if (threadIdx.x == 0) {
        __builtin_amdgcn_fence(__ATOMIC_RELEASE, "agent");   // wbl2: flush h stores device-wide
        unsigned* ep   = bar + bi * 32;                      // epoch line per tile
        unsigned* root = bar + 128 + bi * 32;                // root ctr per tile
        unsigned* gc   = bar + 256 + (blk >> 4) * 32;        // 16 groups of 16 blocks
        unsigned prev = __hip_atomic_fetch_add(gc, 1u, __ATOMIC_RELAXED, __HIP_MEMORY_SCOPE_AGENT);
        if (prev == target * 16u - 1u) {                     // last of my 16-group
            unsigned rprev = __hip_atomic_fetch_add(root, 1u, __ATOMIC_RELAXED, __HIP_MEMORY_SCOPE_AGENT);
            if (rprev == target * 4u - 1u)                   // last of the 4 groups
                __hip_atomic_store(ep, target, __ATOMIC_RELAXED, __HIP_MEMORY_SCOPE_AGENT);
        }
        int guard = 0;
        while (__hip_atomic_load(ep, __ATOMIC_RELAXED, __HIP_MEMORY_SCOPE_AGENT) < target
               && ++guard < (1 << 22)) {
            __builtin_amdgcn_s_sleep(2);
            if ((guard & 255) == 255)                        // stall rescue only
                __builtin_amdgcn_fence(__ATOMIC_ACQUIRE, "agent");
        }
        __builtin_amdgcn_fence(__ATOMIC_ACQUIRE, "workgroup"); // compiler order, s_waitcnt only
    }
    __syncthreads();
}

// ---------------------------------------------------------------------------
// Weights-stationary LSTM scan. 256 blocks = 4 batch-tiles(64 rows) x 64
// h-tiles(8 h-cols). Block's W_hh slice (4 gates x 8 cols x 512 k = 32 KB)
// lives in LDS in fragment-major order (conflict-free ds_read_b128). Per
// step: MFMA gates[64 x 32] from h_t (global) x W(LDS); pointwise cell
// update (c in regs); write h slice; per-batch-tile barrier (h-exchange is
// only within a batch tile). t=0 skips MFMA (h_0 = 0).
// ---------------------------------------------------------------------------
__global__ __launch_bounds__(256) void lstm_scan(
    const unsigned short* __restrict__ Whh,      // [2048,512] bf16
    const unsigned short* __restrict__ emb_proj, // [1000,2048] bf16
    const float* __restrict__ enc_proj,          // [256,2048] fp32 (biases folded)
    const int* __restrict__ tgt,                 // [256,141]
    unsigned short* __restrict__ hs,             // [141,256,512] bf16 (h_1..h_141)
    unsigned* __restrict__ bar)
{
    const int blk = blockIdx.x;
    const int bi  = blk >> 6;        // batch tile 0..3
    const int ht  = blk & 63;        // h tile 0..63
    const int r0  = bi * 64;
    const int h0  = ht * 8;
    const int tid = threadIdx.x;
    const int w    = tid >> 6;
    const int l    = tid & 63;
    const int lr   = l & 15;
    const int quad = l >> 4;
    const int mh = w >> 1;           // m-half 0..1 (which 32 rows)
    const int nf = w & 1;            // n-frag 0..1 (which 16 gate-rows)

    __shared__ unsigned short w_lds[2048 * 8];   // 32 KB fragment-major
    __shared__ float g_lds[64][33];              // gates [row][g*8+hc], padded

    // Stage W slice. Unit u=(nf,k16,quad,lr): 8 bf16 of W row (gr>>3)*512+h0+(gr&7)
    // at cols k16*32+quad*8, where gr = nf*16+lr. Flat unit index == u, so the
    // MFMA-time read addr for lane l is (nf*16+k16)*64 + l  -> conflict-free.
    for (int u = tid; u < 2048; u += 256) {
        const int ulr = u & 15;
        const int uq  = (u >> 4) & 3;
        const int uk  = (u >> 6) & 15;
        const int unf = u >> 10;
        const int gr  = unf * 16 + ulr;
        const int grow = (gr >> 3) * Hdim + h0 + (gr & 7);
        *(bf16x8*)&w_lds[u * 8] =
            *(const bf16x8*)(Whh + (size_t)grow * Hdim + uk * 32 + uq * 8);
    }
    __syncthreads();

    const int prow = tid & 63;           // pointwise: local batch row
    const int phc  = (tid >> 6) * 2;     // pointwise: 2 h-cols
    const int brow = r0 + prow;
    float c0 = 0.f, c1 = 0.f;

    const float* encp = enc_proj + (size_t)brow * G4H + h0;
    const int* tokp   = tgt + (size_t)brow * Sdim;

    const size_t arow0 = (size_t)(r0 + (mh * 2 + 0) * 16 + lr) * Hdim;
    const size_t arow1 = (size_t)(r0 + (mh * 2 + 1) * 16 + lr) * Hdim;
    const unsigned short* wl = w_lds + (size_t)nf * 1024 * 8;

    for (int t = 0; t < Sdim; ++t) {
        f32x4 acc0 = (f32x4){0.f, 0.f, 0.f, 0.f};
        f32x4 acc1 = (f32x4){0.f, 0.f, 0.f, 0.f};
        if (t > 0) {
            const unsigned short* hprev = hs + (size_t)(t - 1) * (Bdim * Hdim);
#pragma unroll
            for (int k16 = 0; k16 < 16; ++k16) {
                const int koff = k16 * 32 + quad * 8;
                bf16x8 a0 = *(const bf16x8*)(hprev + arow0 + koff);
                bf16x8 a1 = *(const bf16x8*)(hprev + arow1 + koff);
                bf16x8 bb = *(const bf16x8*)&wl[(k16 * 64 + l) * 8];
                acc0 = __builtin_amdgcn_mfma_f32_16x16x32_bf16(a0, bb, acc0, 0, 0, 0);
                acc1 = __builtin_amdgcn_mfma_f32_16x16x32_bf16(a1, bb, acc1, 0, 0, 0);
            }
        }
        // C/D: col=lane&15 -> gate-row nf*16+lr; row = quad*4+reg (+ m offsets)
#pragma unroll
        for (int r = 0; r < 4; ++r) {
            g_lds[mh * 32 + quad * 4 + r][nf * 16 + lr]      = acc0[r];
            g_lds[mh * 32 + 16 + quad * 4 + r][nf * 16 + lr] = acc1[r];
        }
        __syncthreads();

        const int tok = tokp[t];
        const unsigned short* embp = emb_proj + (size_t)tok * G4H + h0;
        unsigned hpack = 0;
#pragma unroll
        for (int e = 0; e < 2; ++e) {
            const int hc = phc + e;
            const float iv = g_lds[prow][hc]      + bf2f(embp[hc])              + encp[hc];
            const float fv = g_lds[prow][8 + hc]  + bf2f(embp[Hdim + hc])       + encp[Hdim + hc];
            const float gv = g_lds[prow][16 + hc] + bf2f(embp[2 * Hdim + hc])   + encp[2 * Hdim + hc];
            const float ov = g_lds[prow][24 + hc] + bf2f(embp[3 * Hdim + hc])   + encp[3 * Hdim + hc];
            float c = e ? c1 : c0;
            const float cn = sigmoid_f(fv) * c + sigmoid_f(iv) * tanh_f(gv);
            if (e) c1 = cn; else c0 = cn;
            hpack |= ((unsigned)f2bf(sigmoid_f(ov) * tanh_f(cn))) << (16 * e);
        }
        *(unsigned*)(hs + (size_t)t * (Bdim * Hdim) + (size_t)brow * Hdim + h0 + phc) = hpack;

        if (t != Sdim - 1)
            tile_sync(bar, bi, blk, (unsigned)(t + 1));
    }
}

// ---------------------------------------------------------------------------
// logits = hs[36096,512](bf16) * out_W^T(bf16) + out_b(fp32) -> fp32
// out[b][s][v], row m = s*256 + b.
// ---------------------------------------------------------------------------
__global__ __launch_bounds__(256) void gemm_logits(
    const unsigned short* __restrict__ A,
    const unsigned short* __restrict__ W,
    const float* __restrict__ bias,
    float* __restrict__ out)
{
    const int m0 = blockIdx.x * 128;
    const int n0 = blockIdx.y * 64;
    const int w    = threadIdx.x >> 6;
    const int l    = threadIdx.x & 63;
    const int lr   = l & 15;
    const int quad = l >> 4;

    const unsigned short* pa0 = A + (size_t)(m0 + w * 32 + lr) * Hdim + quad * 8;
    const unsigned short* pa1 = pa0 + (size_t)16 * Hdim;
    const unsigned short* pb[4];
#pragma unroll
    for (int nj = 0; nj < 4; ++nj) {
        int rb = n0 + nj * 16 + lr;
        rb = rb < Vdim ? rb : Vdim - 1;
        pb[nj] = W + (size_t)rb * Hdim + quad * 8;
    }

    f32x4 acc[2][4];
#pragma unroll
    for (int mi = 0; mi < 2; ++mi)
#pragma unroll
        for (int nj = 0; nj < 4; ++nj)
            acc[mi][nj] = (f32x4){0.f, 0.f, 0.f, 0.f};

    for (int k = 0; k < Hdim; k += 32) {
        bf16x8 a0 = *(const bf16x8*)(pa0 + k);
        bf16x8 a1 = *(const bf16x8*)(pa1 + k);
#pragma unroll
        for (int nj = 0; nj < 4; ++nj) {
            bf16x8 bb = *(const bf16x8*)(pb[nj] + k);
            acc[0][nj] = __builtin_amdgcn_mfma_f32_16x16x32_bf16(a0, bb, acc[0][nj], 0, 0, 0);
            acc[1][nj] = __builtin_amdgcn_mfma_f32_16x16x32_bf16(a1, bb, acc[1][nj], 0, 0, 0);
        }
    }

#pragma unroll
    for (int nj = 0; nj < 4; ++nj) {
        const int col = n0 + nj * 16 + lr;
        if (col >= Vdim) continue;
        const float bv = bias[col];
#pragma unroll
        for (int mi = 0; mi < 2; ++mi) {
            const int rowb = m0 + w * 32 + mi * 16 + quad * 4;
#pragma unroll
            for (int r = 0; r < 4; ++r) {
                const int row = rowb + r;            // row = s*256 + b
                const int s = row >> 8;
                const int b = row & 255;
                out[((size_t)b * Sdim + s) * Vdim + col] = acc[mi][nj][r] + bv;
            }
        }
    }
}

extern "C" void kernel_launch(void* const* d_in, const int* in_sizes, int n_in,
                              void* d_out, int out_size, void* d_ws, size_t ws_size,
                              hipStream_t stream) {
    const float* enc   = (const float*)d_in[0];
    const int*   tgt   = (const int*)d_in[1];
    const float* emb   = (const float*)d_in[2];
    const float* W_ih  = (const float*)d_in[3];
    const float* W_hh  = (const float*)d_in[4];
    const float* b_ih  = (const float*)d_in[5];
    const float* b_hh  = (const float*)d_in[6];
    // d_in[7..9]: attn_W / attn_b / v_w — dead code (softmax over 1 source pos)
    const float* out_W = (const float*)d_in[10];
    const float* out_b = (const float*)d_in[11];
    float* out = (float*)d_out;

    char* ws = (char*)d_ws;
    unsigned short* whh_bf   = (unsigned short*)ws;                     // 2,097,152 B
    unsigned short* outw_bf  = (unsigned short*)(ws + 2097152);         // 1,024,000 B
    unsigned short* emb_proj = (unsigned short*)(ws + 3121152);         // 4,096,000 B
    float*          enc_proj = (float*)(ws + 7217152);                  // 2,097,152 B
    unsigned short* hs       = (unsigned short*)(ws + 9314304);         // 36,962,304 B
    unsigned*       bar      = (unsigned*)(ws + 46276608);              // 4,096 B
    // total ws use = 46,280,704 B

    hipMemsetAsync(bar, 0, 4096, stream);   // barrier counters (re-poisoned each call)

    f32_to_bf16_4<<<dim3((262144 + 255) / 256), 256, 0, stream>>>(
        (const float4*)W_hh, (u16x4*)whh_bf, 262144);
    f32_to_bf16_4<<<dim3((128000 + 255) / 256), 256, 0, stream>>>(
        (const float4*)out_W, (u16x4*)outw_bf, 128000);

    // emb_proj = embedding @ W_ih[:, :E].T               (bf16, [1000,2048])
    gemm_bt_f32in<true><<<dim3(8, 32), 256, 0, stream>>>(
        emb, Edim, Vdim, W_ih, 2 * Edim, emb_proj, G4H, nullptr, nullptr, Edim);
    // enc_proj = encoder_output @ W_ih[:, E:].T + b_ih + b_hh   (fp32, [256,2048])
    gemm_bt_f32in<false><<<dim3(2, 32), 256, 0, stream>>>(
        enc, Edim, Bdim, W_ih + Edim, 2 * Edim, enc_proj, G4H, b_ih, b_hh, Edim);
    // weights-stationary scan: 256 blocks, per-batch-tile barrier
    lstm_scan<<<dim3(256), 256, 0, stream>>>(whh_bf, emb_proj, enc_proj, tgt, hs, bar);
    // logits = hs @ out_W.T + out_b   (fp32 out)
    gemm_logits<<<dim3(282, 16), 256, 0, stream>>>(hs, outw_bf, out_b, out);
}

// Round 2
// 1511.310 us; speedup vs baseline: 4.2306x; 1.4679x over previous
//
#include <hip/hip_runtime.h>

typedef __attribute__((ext_vector_type(8))) short bf16x8;
typedef __attribute__((ext_vector_type(4))) float f32x4;
typedef __attribute__((ext_vector_type(4))) unsigned short u16x4;

#define Bdim 256
#define Sdim 141
#define Vdim 1000
#define Edim 256
#define Hdim 512
#define G4H  2048

__device__ __forceinline__ float bf2f(unsigned short u) {
    union { unsigned int i; float f; } x; x.i = ((unsigned int)u) << 16; return x.f;
}
__device__ __forceinline__ unsigned short f2bf(float f) {
    union { float f; unsigned int i; } x; x.f = f;
    unsigned int i = x.i;
    return (unsigned short)((i + 0x7FFFu + ((i >> 16) & 1u)) >> 16);  // RNE
}
__device__ __forceinline__ float sigmoid_f(float x) { return 1.f / (1.f + __expf(-x)); }
__device__ __forceinline__ float tanh_f(float x)    { return 1.f - 2.f / (__expf(2.f * x) + 1.f); }

__device__ __forceinline__ bf16x8 cvt8(const float* p) {
    const float4 v0 = ((const float4*)p)[0];
    const float4 v1 = ((const float4*)p)[1];
    bf16x8 r;
    r[0] = (short)f2bf(v0.x); r[1] = (short)f2bf(v0.y);
    r[2] = (short)f2bf(v0.z); r[3] = (short)f2bf(v0.w);
    r[4] = (short)f2bf(v1.x); r[5] = (short)f2bf(v1.y);
    r[6] = (short)f2bf(v1.z); r[7] = (short)f2bf(v1.w);
    return r;
}

// ---------------------------------------------------------------------------
// Bulk fp32 -> bf16 (RNE), vectorized x4.
// ---------------------------------------------------------------------------
__global__ __launch_bounds__(256) void f32_to_bf16_4(
    const float4* __restrict__ src, u16x4* __restrict__ dst, int n4)
{
    const int i = blockIdx.x * 256 + threadIdx.x;
    if (i < n4) {
        const float4 v = src[i];
        u16x4 r;
        r[0] = f2bf(v.x); r[1] = f2bf(v.y); r[2] = f2bf(v.z); r[3] = f2bf(v.w);
        dst[i] = r;
    }
}

// ---------------------------------------------------------------------------
// C = A * B^T (+bias), fp32 inputs converted inline to bf16 for MFMA.
// Tile 128x64, 4 waves. Layouts verified (m89/m92).
// ---------------------------------------------------------------------------
template <bool BF16OUT>
__global__ __launch_bounds__(256) void gemm_bt_f32in(
    const float* __restrict__ A, int lda, int M,
    const float* __restrict__ Bw, int ldb,
    void* __restrict__ Cv, int ldc,
    const float* __restrict__ bias0,
    const float* __restrict__ bias1,
    int K)
{
    const int m0 = blockIdx.x * 128;
    const int n0 = blockIdx.y * 64;
    const int w    = threadIdx.x >> 6;
    const int l    = threadIdx.x & 63;
    const int lr   = l & 15;
    const int quad = l >> 4;

    int ra0 = m0 + w * 32 + lr;
    int ra1 = ra0 + 16;
    ra0 = ra0 < M ? ra0 : M - 1;
    ra1 = ra1 < M ? ra1 : M - 1;
    const float* pa0 = A + (size_t)ra0 * lda + quad * 8;
    const float* pa1 = A + (size_t)ra1 * lda + quad * 8;
    const float* pb[4];
#pragma unroll
    for (int nj = 0; nj < 4; ++nj)
        pb[nj] = Bw + (size_t)(n0 + nj * 16 + lr) * ldb + quad * 8;

    f32x4 acc[2][4];
#pragma unroll
    for (int mi = 0; mi < 2; ++mi)
#pragma unroll
        for (int nj = 0; nj < 4; ++nj)
            acc[mi][nj] = (f32x4){0.f, 0.f, 0.f, 0.f};

    for (int k = 0; k < K; k += 32) {
        bf16x8 a0 = cvt8(pa0 + k);
        bf16x8 a1 = cvt8(pa1 + k);
#pragma unroll
        for (int nj = 0; nj < 4; ++nj) {
            bf16x8 bb = cvt8(pb[nj] + k);
            acc[0][nj] = __builtin_amdgcn_mfma_f32_16x16x32_bf16(a0, bb, acc[0][nj], 0, 0, 0);
            acc[1][nj] = __builtin_amdgcn_mfma_f32_16x16x32_bf16(a1, bb, acc[1][nj], 0, 0, 0);
        }
    }

#pragma unroll
    for (int nj = 0; nj < 4; ++nj) {
        const int col = n0 + nj * 16 + lr;
        float bv = 0.f;
        if (bias0) bv += bias0[col];
        if (bias1) bv += bias1[col];
#pragma unroll
        for (int mi = 0; mi < 2; ++mi) {
            const int row = m0 + w * 32 + mi * 16 + quad * 4;
#pragma unroll
            for (int r = 0; r < 4; ++r) {
                if (row + r < M) {
                    const float v = acc[mi][nj][r] + bv;
                    if (BF16OUT)
                        ((unsigned short*)Cv)[(size_t)(row + r) * ldc + col] = f2bf(v);
                    else
                        ((float*)Cv)[(size_t)(row + r) * ldc + col] = v;
                }
            }
        }
    }
}

// ---------------------------------------------------------------------------
// Per-batch-tile grid barrier: 64 blocks (same bi) rendezvous. Monotonic
// counters (NO resets). Group g (16 logical blocks) done in epoch `target`
// when its counter reaches target*16; tile root done at target*4; then
// epoch[bi] = target. Bounded spin: logic bug -> finite wrong answer, no hang.
//
// Memory-order rationale (v3 — NO per-step cache maintenance at all):
//  - hs stores are agent-scope RELAXED ATOMIC stores (global_store sc0 sc1):
//    they go THROUGH to the coherent point, leaving no dirty L2 state.
//    -> no buffer_wbl2 release fence needed. __syncthreads() drains each
//    wave's vmcnt(0), so all stores are acked at the coherent point before
//    thread 0 issues the arrival RMW (which lands at the same point).
//  - Readers need no invalidate: hs[t] lives at VIRGIN addresses each step;
//    writes never allocate in any L2 (write-through), so the first-touch
//    read fill at t+1 pulls the fully-merged line from L3. enc/emb/Whh are
//    read-only and stay L2-resident across the whole scan.
//  - Hedge: if the spin stalls (>256 polls) re-issue an agent-acquire
//    fence — free on the normal path, bounds staleness if wrong.
// ---------------------------------------------------------------------------
__device__ __forceinline__ void tile_sync(unsigned* bar, int bi, int lbi, unsigned target) {
    __syncthreads();   // drains vmcnt(0) per wave: hs stores acked at coherent point
    if (threadIdx.x == 0) {
        unsigned* ep   = bar + bi * 32;                      // epoch line per tile
        unsigned* root = bar + 128 + bi * 32;                // root ctr per tile
        unsigned* gc   = bar + 256 + (lbi >> 4) * 32;        // 16 groups of 16 blocks
        unsigned prev = __hip_atomic_fetch_add(gc, 1u, __ATOMIC_RELAXED, __HIP_MEMORY_SCOPE_AGENT);
        if (prev == target * 16u - 1u) {                     // last of my 16-group
            unsigned rprev = __hip_atomic_fetch_add(root, 1u, __ATOMIC_RELAXED, __HIP_MEMORY_SCOPE_AGENT);
            if (rprev == target * 4u - 1u)                   // last of the 4 groups
                __hip_atomic_store(ep, target, __ATOMIC_RELAXED, __HIP_MEMORY_SCOPE_AGENT);
        }
        int guard = 0;
        while (__hip_atomic_load(ep, __ATOMIC_RELAXED, __HIP_MEMORY_SCOPE_AGENT) < target
               && ++guard < (1 << 22)) {
            __builtin_amdgcn_s_sleep(2);
            if ((guard & 255) == 255)                        // stall rescue only
                __builtin_amdgcn_fence(__ATOMIC_ACQUIRE, "agent");
        }
        __builtin_amdgcn_fence(__ATOMIC_ACQUIRE, "workgroup"); // compiler order, s_waitcnt only
    }
    __syncthreads();
}

// ---------------------------------------------------------------------------
// Weights-stationary LSTM scan. 256 blocks = 4 batch-tiles(64 rows) x 64
// h-tiles(8 h-cols). Logical block id remapped so 32 consecutive logical
// blocks share an XCD (dispatch round-robins blockIdx % 8): a batch tile's
// 64 blocks then span 2 XCDs, cutting per-step L3->L2 h duplication 4x.
// Block's W_hh slice (32 KB) in LDS, fragment-major (conflict-free
// ds_read_b128). Per step: preload emb/enc gather (token-dependent, hidden
// under MFMA); MFMA gates[64x32] from h_t x W(LDS); pointwise cell update
// (c in regs); write h slice WRITE-THROUGH (agent atomic store);
// per-batch-tile barrier. t=0 skips MFMA (h_0 = 0).
// ---------------------------------------------------------------------------
__global__ __launch_bounds__(256) void lstm_scan(
    const unsigned short* __restrict__ Whh,      // [2048,512] bf16
    const unsigned short* __restrict__ emb_proj, // [1000,2048] bf16
    const float* __restrict__ enc_proj,          // [256,2048] fp32 (biases folded)
    const int* __restrict__ tgt,                 // [256,141]
    unsigned short* __restrict__ hs,             // [141,256,512] bf16 (h_1..h_141)
    unsigned* __restrict__ bar)
{
    const int blk = blockIdx.x;
    const int lbi = (blk & 7) * 32 + (blk >> 3);  // logical id: 32 consecutive per XCD
    const int bi  = lbi >> 6;        // batch tile 0..3
    const int ht  = lbi & 63;        // h tile 0..63
    const int r0  = bi * 64;
    const int h0  = ht * 8;
    const int tid = threadIdx.x;
    const int w    = tid >> 6;
    const int l    = tid & 63;
    const int lr   = l & 15;
    const int quad = l >> 4;
    const int mh = w >> 1;           // m-half 0..1 (which 32 rows)
    const int nf = w & 1;            // n-frag 0..1 (which 16 gate-rows)

    __shared__ unsigned short w_lds[2048 * 8];   // 32 KB fragment-major
    __shared__ float g_lds[64][33];              // gates [row][g*8+hc], padded

    // Stage W slice. Unit u=(nf,k16,quad,lr): 8 bf16 of W row (gr>>3)*512+h0+(gr&7)
    // at cols k16*32+quad*8, where gr = nf*16+lr. Flat unit index == u, so the
    // MFMA-time read addr for lane l is (nf*16+k16)*64 + l  -> conflict-free.
    for (int u = tid; u < 2048; u += 256) {
        const int ulr = u & 15;
        const int uq  = (u >> 4) & 3;
        const int uk  = (u >> 6) & 15;
        const int unf = u >> 10;
        const int gr  = unf * 16 + ulr;
        const int grow = (gr >> 3) * Hdim + h0 + (gr & 7);
        *(bf16x8*)&w_lds[u * 8] =
            *(const bf16x8*)(Whh + (size_t)grow * Hdim + uk * 32 + uq * 8);
    }
    __syncthreads();

    const int prow = tid & 63;           // pointwise: local batch row
    const int phc  = (tid >> 6) * 2;     // pointwise: 2 h-cols
    const int brow = r0 + prow;
    float c0 = 0.f, c1 = 0.f;

    const float* encp = enc_proj + (size_t)brow * G4H + h0;
    const int* tokp   = tgt + (size_t)brow * Sdim;

    const size_t arow0 = (size_t)(r0 + (mh * 2 + 0) * 16 + lr) * Hdim;
    const size_t arow1 = (size_t)(r0 + (mh * 2 + 1) * 16 + lr) * Hdim;
    const unsigned short* wl = w_lds + (size_t)nf * 1024 * 8;

    for (int t = 0; t < Sdim; ++t) {
        // --- preload token-dependent gather + enc slice (independent of h;
        //     latency hides under the MFMA loop) ---
        const int tok = tokp[t];
        const unsigned short* embp = emb_proj + (size_t)tok * G4H + h0;
        unsigned epk[4];
        float2   env[4];
#pragma unroll
        for (int g = 0; g < 4; ++g) {
            epk[g] = *(const unsigned*)(embp + g * Hdim + phc);   // 2 bf16
            env[g] = *(const float2*)(encp + g * Hdim + phc);     // 2 f32
        }

        f32x4 acc0 = (f32x4){0.f, 0.f, 0.f, 0.f};
        f32x4 acc1 = (f32x4){0.f, 0.f, 0.f, 0.f};
        if (t > 0) {
            const unsigned short* hprev = hs + (size_t)(t - 1) * (Bdim * Hdim);
#pragma unroll
            for (int k16 = 0; k16 < 16; ++k16) {
                const int koff = k16 * 32 + quad * 8;
                bf16x8 a0 = *(const bf16x8*)(hprev + arow0 + koff);
                bf16x8 a1 = *(const bf16x8*)(hprev + arow1 + koff);
                bf16x8 bb = *(const bf16x8*)&wl[(k16 * 64 + l) * 8];
                acc0 = __builtin_amdgcn_mfma_f32_16x16x32_bf16(a0, bb, acc0, 0, 0, 0);
                acc1 = __builtin_amdgcn_mfma_f32_16x16x32_bf16(a1, bb, acc1, 0, 0, 0);
            }
        }
        // C/D: col=lane&15 -> gate-row nf*16+lr; row = quad*4+reg (+ m offsets)
#pragma unroll
        for (int r = 0; r < 4; ++r) {
            g_lds[mh * 32 + quad * 4 + r][nf * 16 + lr]      = acc0[r];
            g_lds[mh * 32 + 16 + quad * 4 + r][nf * 16 + lr] = acc1[r];
        }
        __syncthreads();

        unsigned hpack = 0;
#pragma unroll
        for (int e = 0; e < 2; ++e) {
            const int hc = phc + e;
            const float iv = g_lds[prow][hc]      + bf2f((unsigned short)(epk[0] >> (16 * e))) + (e ? env[0].y : env[0].x);
            const float fv = g_lds[prow][8 + hc]  + bf2f((unsigned short)(epk[1] >> (16 * e))) + (e ? env[1].y : env[1].x);
            const float gv = g_lds[prow][16 + hc] + bf2f((unsigned short)(epk[2] >> (16 * e))) + (e ? env[2].y : env[2].x);
            const float ov = g_lds[prow][24 + hc] + bf2f((unsigned short)(epk[3] >> (16 * e))) + (e ? env[3].y : env[3].x);
            float c = e ? c1 : c0;
            const float cn = sigmoid_f(fv) * c + sigmoid_f(iv) * tanh_f(gv);
            if (e) c1 = cn; else c0 = cn;
            hpack |= ((unsigned)f2bf(sigmoid_f(ov) * tanh_f(cn))) << (16 * e);
        }
        // WRITE-THROUGH store: no dirty L2 state, no release fence needed.
        unsigned* hsp = (unsigned*)(hs + (size_t)t * (Bdim * Hdim) + (size_t)brow * Hdim + h0 + phc);
        __hip_atomic_store(hsp, hpack, __ATOMIC_RELAXED, __HIP_MEMORY_SCOPE_AGENT);

        if (t != Sdim - 1)
            tile_sync(bar, bi, lbi, (unsigned)(t + 1));
    }
}

// ---------------------------------------------------------------------------
// logits = hs[36096,512](bf16) * out_W^T(bf16) + out_b(fp32) -> fp32
// out[b][s][v], row m = s*256 + b.
// ---------------------------------------------------------------------------
__global__ __launch_bounds__(256) void gemm_logits(
    const unsigned short* __restrict__ A,
    const unsigned short* __restrict__ W,
    const float* __restrict__ bias,
    float* __restrict__ out)
{
    const int m0 = blockIdx.x * 128;
    const int n0 = blockIdx.y * 64;
    const int w    = threadIdx.x >> 6;
    const int l    = threadIdx.x & 63;
    const int lr   = l & 15;
    const int quad = l >> 4;

    const unsigned short* pa0 = A + (size_t)(m0 + w * 32 + lr) * Hdim + quad * 8;
    const unsigned short* pa1 = pa0 + (size_t)16 * Hdim;
    const unsigned short* pb[4];
#pragma unroll
    for (int nj = 0; nj < 4; ++nj) {
        int rb = n0 + nj * 16 + lr;
        rb = rb < Vdim ? rb : Vdim - 1;
        pb[nj] = W + (size_t)rb * Hdim + quad * 8;
    }

    f32x4 acc[2][4];
#pragma unroll
    for (int mi = 0; mi < 2; ++mi)
#pragma unroll
        for (int nj = 0; nj < 4; ++nj)
            acc[mi][nj] = (f32x4){0.f, 0.f, 0.f, 0.f};

    for (int k = 0; k < Hdim; k += 32) {
        bf16x8 a0 = *(const bf16x8*)(pa0 + k);
        bf16x8 a1 = *(const bf16x8*)(pa1 + k);
#pragma unroll
        for (int nj = 0; nj < 4; ++nj) {
            bf16x8 bb = *(const bf16x8*)(pb[nj] + k);
            acc[0][nj] = __builtin_amdgcn_mfma_f32_16x16x32_bf16(a0, bb, acc[0][nj], 0, 0, 0);
            acc[1][nj] = __builtin_amdgcn_mfma_f32_16x16x32_bf16(a1, bb, acc[1][nj], 0, 0, 0);
        }
    }

#pragma unroll
    for (int nj = 0; nj < 4; ++nj) {
        const int col = n0 + nj * 16 + lr;
        if (col >= Vdim) continue;
        const float bv = bias[col];
#pragma unroll
        for (int mi = 0; mi < 2; ++mi) {
            const int rowb = m0 + w * 32 + mi * 16 + quad * 4;
#pragma unroll
            for (int r = 0; r < 4; ++r) {
                const int row = rowb + r;            // row = s*256 + b
                const int s = row >> 8;
                const int b = row & 255;
                out[((size_t)b * Sdim + s) * Vdim + col] = acc[mi][nj][r] + bv;
            }
        }
    }
}

extern "C" void kernel_launch(void* const* d_in, const int* in_sizes, int n_in,
                              void* d_out, int out_size, void* d_ws, size_t ws_size,
                              hipStream_t stream) {
    const float* enc   = (const float*)d_in[0];
    const int*   tgt   = (const int*)d_in[1];
    const float* emb   = (const float*)d_in[2];
    const float* W_ih  = (const float*)d_in[3];
    const float* W_hh  = (const float*)d_in[4];
    const float* b_ih  = (const float*)d_in[5];
    const float* b_hh  = (const float*)d_in[6];
    // d_in[7..9]: attn_W / attn_b / v_w — dead code (softmax over 1 source pos)
    const float* out_W = (const float*)d_in[10];
    const float* out_b = (const float*)d_in[11];
    float* out = (float*)d_out;

    char* ws = (char*)d_ws;
    unsigned short* whh_bf   = (unsigned short*)ws;                     // 2,097,152 B
    unsigned short* outw_bf  = (unsigned short*)(ws + 2097152);         // 1,024,000 B
    unsigned short* emb_proj = (unsigned short*)(ws + 3121152);         // 4,096,000 B
    float*          enc_proj = (float*)(ws + 7217152);                  // 2,097,152 B
    unsigned short* hs       = (unsigned short*)(ws + 9314304);         // 36,962,304 B
    unsigned*       bar      = (unsigned*)(ws + 46276608);              // 4,096 B
    // total ws use = 46,280,704 B

    hipMemsetAsync(bar, 0, 4096, stream);   // barrier counters (re-poisoned each call)

    f32_to_bf16_4<<<dim3((262144 + 255) / 256), 256, 0, stream>>>(
        (const float4*)W_hh, (u16x4*)whh_bf, 262144);
    f32_to_bf16_4<<<dim3((128000 + 255) / 256), 256, 0, stream>>>(
        (const float4*)out_W, (u16x4*)outw_bf, 128000);

    // emb_proj = embedding @ W_ih[:, :E].T               (bf16, [1000,2048])
    gemm_bt_f32in<true><<<dim3(8, 32), 256, 0, stream>>>(
        emb, Edim, Vdim, W_ih, 2 * Edim, emb_proj, G4H, nullptr, nullptr, Edim);
    // enc_proj = encoder_output @ W_ih[:, E:].T + b_ih + b_hh   (fp32, [256,2048])
    gemm_bt_f32in<false><<<dim3(2, 32), 256, 0, stream>>>(
        enc, Edim, Bdim, W_ih + Edim, 2 * Edim, enc_proj, G4H, b_ih, b_hh, Edim);
    // weights-stationary scan: 256 blocks, per-batch-tile barrier
    lstm_scan<<<dim3(256), 256, 0, stream>>>(whh_bf, emb_proj, enc_proj, tgt, hs, bar);
    // logits = hs @ out_W.T + out_b   (fp32 out)
    gemm_logits<<<dim3(282, 16), 256, 0, stream>>>(hs, outw_bf, out_b, out);
}

// Round 3
// 1450.216 us; speedup vs baseline: 4.4089x; 1.0421x over previous
//
#include <hip/hip_runtime.h>

typedef __attribute__((ext_vector_type(8))) short bf16x8;
typedef __attribute__((ext_vector_type(4))) float f32x4;
typedef __attribute__((ext_vector_type(4))) unsigned short u16x4;

#define Bdim 256
#define Sdim 141
#define Vdim 1000
#define Edim 256
#define Hdim 512
#define G4H  2048

__device__ __forceinline__ float bf2f(unsigned short u) {
    union { unsigned int i; float f; } x; x.i = ((unsigned int)u) << 16; return x.f;
}
__device__ __forceinline__ unsigned short f2bf(float f) {
    union { float f; unsigned int i; } x; x.f = f;
    unsigned int i = x.i;
    return (unsigned short)((i + 0x7FFFu + ((i >> 16) & 1u)) >> 16);  // RNE
}
__device__ __forceinline__ float sigmoid_f(float x) { return 1.f / (1.f + __expf(-x)); }
__device__ __forceinline__ float tanh_f(float x)    { return 1.f - 2.f / (__expf(2.f * x) + 1.f); }

__device__ __forceinline__ bf16x8 cvt8(const float* p) {
    const float4 v0 = ((const float4*)p)[0];
    const float4 v1 = ((const float4*)p)[1];
    bf16x8 r;
    r[0] = (short)f2bf(v0.x); r[1] = (short)f2bf(v0.y);
    r[2] = (short)f2bf(v0.z); r[3] = (short)f2bf(v0.w);
    r[4] = (short)f2bf(v1.x); r[5] = (short)f2bf(v1.y);
    r[6] = (short)f2bf(v1.z); r[7] = (short)f2bf(v1.w);
    return r;
}

// ---------------------------------------------------------------------------
// Bulk fp32 -> bf16 (RNE), vectorized x4.
// ---------------------------------------------------------------------------
__global__ __launch_bounds__(256) void f32_to_bf16_4(
    const float4* __restrict__ src, u16x4* __restrict__ dst, int n4)
{
    const int i = blockIdx.x * 256 + threadIdx.x;
    if (i < n4) {
        const float4 v = src[i];
        u16x4 r;
        r[0] = f2bf(v.x); r[1] = f2bf(v.y); r[2] = f2bf(v.z); r[3] = f2bf(v.w);
        dst[i] = r;
    }
}

// ---------------------------------------------------------------------------
// C = A * B^T (+bias), fp32 inputs converted inline to bf16 for MFMA.
// Tile 128x64, 4 waves. Layouts verified (m89/m92).
// ---------------------------------------------------------------------------
template <bool BF16OUT>
__global__ __launch_bounds__(256) void gemm_bt_f32in(
    const float* __restrict__ A, int lda, int M,
    const float* __restrict__ Bw, int ldb,
    void* __restrict__ Cv, int ldc,
    const float* __restrict__ bias0,
    const float* __restrict__ bias1,
    int K)
{
    const int m0 = blockIdx.x * 128;
    const int n0 = blockIdx.y * 64;
    const int w    = threadIdx.x >> 6;
    const int l    = threadIdx.x & 63;
    const int lr   = l & 15;
    const int quad = l >> 4;

    int ra0 = m0 + w * 32 + lr;
    int ra1 = ra0 + 16;
    ra0 = ra0 < M ? ra0 : M - 1;
    ra1 = ra1 < M ? ra1 : M - 1;
    const float* pa0 = A + (size_t)ra0 * lda + quad * 8;
    const float* pa1 = A + (size_t)ra1 * lda + quad * 8;
    const float* pb[4];
#pragma unroll
    for (int nj = 0; nj < 4; ++nj)
        pb[nj] = Bw + (size_t)(n0 + nj * 16 + lr) * ldb + quad * 8;

    f32x4 acc[2][4];
#pragma unroll
    for (int mi = 0; mi < 2; ++mi)
#pragma unroll
        for (int nj = 0; nj < 4; ++nj)
            acc[mi][nj] = (f32x4){0.f, 0.f, 0.f, 0.f};

    for (int k = 0; k < K; k += 32) {
        bf16x8 a0 = cvt8(pa0 + k);
        bf16x8 a1 = cvt8(pa1 + k);
#pragma unroll
        for (int nj = 0; nj < 4; ++nj) {
            bf16x8 bb = cvt8(pb[nj] + k);
            acc[0][nj] = __builtin_amdgcn_mfma_f32_16x16x32_bf16(a0, bb, acc[0][nj], 0, 0, 0);
            acc[1][nj] = __builtin_amdgcn_mfma_f32_16x16x32_bf16(a1, bb, acc[1][nj], 0, 0, 0);
        }
    }

#pragma unroll
    for (int nj = 0; nj < 4; ++nj) {
        const int col = n0 + nj * 16 + lr;
        float bv = 0.f;
        if (bias0) bv += bias0[col];
        if (bias1) bv += bias1[col];
#pragma unroll
        for (int mi = 0; mi < 2; ++mi) {
            const int row = m0 + w * 32 + mi * 16 + quad * 4;
#pragma unroll
            for (int r = 0; r < 4; ++r) {
                if (row + r < M) {
                    const float v = acc[mi][nj][r] + bv;
                    if (BF16OUT)
                        ((unsigned short*)Cv)[(size_t)(row + r) * ldc + col] = f2bf(v);
                    else
                        ((float*)Cv)[(size_t)(row + r) * ldc + col] = v;
                }
            }
        }
    }
}

// ---------------------------------------------------------------------------
// Per-tile barrier: 32 blocks (one XCD in the fast layout) rendezvous.
// Monotonic counter (NO resets): epoch `target` done when counter hits
// target*32; then epoch word = target. All atomics RELAXED agent-scope
// (serialize at the coherent point; no per-op L2 writeback/invalidate).
// Bounded spin: a logic bug gives a finite wrong answer, not a hang.
// Ordering: __syncthreads() on entry drains each wave's vmcnt(0), so all h
// stores are acked (L2 for plain stores, coherent point for write-through)
// before thread 0's arrival RMW. Readers: fast path reads hit the same XCD
// L2 the writers dirtied; slow path reads fill from the coherent point;
// virgin addresses each step -> no stale cache copies anywhere.
// ---------------------------------------------------------------------------
__device__ __forceinline__ void tile_sync(unsigned* bar, int bi, unsigned target) {
    __syncthreads();   // drains vmcnt(0): h stores acked before arrival
    if (threadIdx.x == 0) {
        unsigned* ep  = bar + bi * 32;            // epoch word (own 128B line)
        unsigned* ctr = bar + 256 + bi * 32;      // arrival counter
        unsigned prev = __hip_atomic_fetch_add(ctr, 1u, __ATOMIC_RELAXED, __HIP_MEMORY_SCOPE_AGENT);
        if (prev == target * 32u - 1u)
            __hip_atomic_store(ep, target, __ATOMIC_RELAXED, __HIP_MEMORY_SCOPE_AGENT);
        int guard = 0;
        while (__hip_atomic_load(ep, __ATOMIC_RELAXED, __HIP_MEMORY_SCOPE_AGENT) < target
               && ++guard < (1 << 22)) {
            __builtin_amdgcn_s_sleep(1);
            if ((guard & 255) == 255)                        // stall rescue only
                __builtin_amdgcn_fence(__ATOMIC_ACQUIRE, "agent");
        }
        __builtin_amdgcn_fence(__ATOMIC_ACQUIRE, "workgroup"); // compiler order, s_waitcnt only
    }
    __syncthreads();
}

// ---------------------------------------------------------------------------
// Weights-stationary LSTM scan, XCD-local h exchange.
// 256 blocks = 8 batch-tiles(32 rows) x 32 h-tiles(16 h-cols). Tile bi =
// blk&7: with round-robin dispatch all 32 blocks of a tile land on XCD bi,
// so the h exchange (all-to-all within a tile) stays inside one L2 ->
// plain write-back stores + plain reads, no cache maintenance at all.
// CORRECTNESS GUARD (mapping is not architecturally guaranteed): each block
// reads HW_REG_XCC_ID and ORs a per-tile XCD bitmask; after the init
// barrier, tiles whose 32 blocks do NOT share an XCD fall back to
// write-through agent-scope atomic h stores (the proven round-2 scheme).
// Wrong mapping degrades speed, never correctness.
// Per wave: one gate (i/f/g/o), 16 gate-rows x 32 batch rows, K=512 from
// fragment-major LDS W (64 KB, conflict-free ds_read_b128). Pointwise cell
// update keeps c in regs; h written as packed u32 (32B/row/block -> full
// sectors). t=0 skips MFMA (h_0 = 0).
// ---------------------------------------------------------------------------
__global__ __launch_bounds__(256) void lstm_scan(
    const unsigned short* __restrict__ Whh,      // [2048,512] bf16
    const unsigned short* __restrict__ emb_proj, // [1000,2048] bf16
    const float* __restrict__ enc_proj,          // [256,2048] fp32 (biases folded)
    const int* __restrict__ tgt,                 // [256,141]
    unsigned short* __restrict__ hs,             // [141,256,512] bf16 (h_1..h_141)
    unsigned* __restrict__ bar)
{
    const int blk = blockIdx.x;
    const int bi  = blk & 7;         // batch tile 0..7 == XCD (round-robin)
    const int ht  = blk >> 3;        // h tile 0..31 (16 cols)
    const int r0  = bi * 32;
    const int h0  = ht * 16;
    const int tid = threadIdx.x;
    const int nf   = tid >> 6;       // wave = gate 0..3 (i,f,g,o)
    const int l    = tid & 63;
    const int lr   = l & 15;
    const int quad = l >> 4;

    __shared__ unsigned short w_lds[4096 * 8];   // 64 KB fragment-major
    __shared__ float g_lds[32][67];              // gates [row][g*16+c]

    // Stage W slice. Unit u=(g,k16,quad,lr): 8 bf16 of W row g*512+h0+lr at
    // cols k16*32+quad*8. Flat unit index == u, so the MFMA-time read addr
    // for wave nf, lane l is ((nf*16+k16)*64 + l) -> conflict-free b128.
    for (int u = tid; u < 4096; u += 256) {
        const int ulr = u & 15;
        const int uq  = (u >> 4) & 3;
        const int uk  = (u >> 6) & 15;
        const int ug  = u >> 10;
        *(bf16x8*)&w_lds[u * 8] =
            *(const bf16x8*)(Whh + (size_t)(ug * Hdim + h0 + ulr) * Hdim + uk * 32 + uq * 8);
    }

    // XCD-placement guard: OR my physical XCD into the tile's bitmask.
    int xcc;
    asm volatile("s_getreg_b32 %0, hwreg(HW_REG_XCC_ID)" : "=s"(xcc));
    if (tid == 0) {
        __hip_atomic_fetch_or(bar + 512 + bi * 32, 1u << (xcc & 7),
                              __ATOMIC_RELAXED, __HIP_MEMORY_SCOPE_AGENT);
        asm volatile("s_waitcnt vmcnt(0)" ::: "memory");   // OR acked before arrival
    }
    tile_sync(bar, bi, 1u);                                 // also covers W staging
    const unsigned fl = __hip_atomic_load(bar + 512 + bi * 32,
                              __ATOMIC_RELAXED, __HIP_MEMORY_SCOPE_AGENT);
    const bool fast = (fl & (fl - 1u)) == 0u;   // all 32 blocks on one XCD

    const int prow = tid & 31;           // pointwise: local batch row
    const int phc  = (tid >> 5) * 2;     // pointwise: 2 of my 16 h-cols
    const int brow = r0 + prow;

    const float* encp = enc_proj + (size_t)brow * G4H + h0 + phc;
    const int* tokp   = tgt + (size_t)brow * Sdim;

    const size_t arow0 = (size_t)(r0 + lr) * Hdim + quad * 8;
    const size_t arow1 = (size_t)(r0 + 16 + lr) * Hdim + quad * 8;
    const unsigned short* wlp = w_lds + (size_t)nf * 1024 * 8;

    float c0 = 0.f, c1 = 0.f;

    for (int t = 0; t < Sdim; ++t) {
        // --- preload token gather + enc slice (independent of h; latency
        //     hides under the MFMA loop) ---
        const int tok = tokp[t];
        const unsigned short* embp = emb_proj + (size_t)tok * G4H + h0 + phc;
        unsigned epk[4];
        float2   env[4];
#pragma unroll
        for (int g = 0; g < 4; ++g) {
            epk[g] = *(const unsigned*)(embp + g * Hdim);   // 2 bf16
            env[g] = *(const float2*)(encp + g * Hdim);     // 2 f32
        }

        f32x4 acc0 = (f32x4){0.f, 0.f, 0.f, 0.f};
        f32x4 acc1 = (f32x4){0.f, 0.f, 0.f, 0.f};
        if (t > 0) {
            const unsigned short* hprev = hs + (size_t)(t - 1) * (Bdim * Hdim);
#pragma unroll
            for (int k16 = 0; k16 < 16; ++k16) {
                bf16x8 a0 = *(const bf16x8*)(hprev + arow0 + k16 * 32);
                bf16x8 a1 = *(const bf16x8*)(hprev + arow1 + k16 * 32);
                bf16x8 bb = *(const bf16x8*)&wlp[(k16 * 64 + l) * 8];
                acc0 = __builtin_amdgcn_mfma_f32_16x16x32_bf16(a0, bb, acc0, 0, 0, 0);
                acc1 = __builtin_amdgcn_mfma_f32_16x16x32_bf16(a1, bb, acc1, 0, 0, 0);
            }
        }
        // C/D: col=lane&15 -> gate-row nf*16+lr; row = quad*4+reg (+16 for acc1)
#pragma unroll
        for (int r = 0; r < 4; ++r) {
            g_lds[quad * 4 + r][nf * 16 + lr]      = acc0[r];
            g_lds[16 + quad * 4 + r][nf * 16 + lr] = acc1[r];
        }
        __syncthreads();

        unsigned hpack = 0;
#pragma unroll
        for (int e = 0; e < 2; ++e) {
            const int c = phc + e;
            const float iv = g_lds[prow][c]      + bf2f((unsigned short)(epk[0] >> (16 * e))) + (e ? env[0].y : env[0].x);
            const float fv = g_lds[prow][16 + c] + bf2f((unsigned short)(epk[1] >> (16 * e))) + (e ? env[1].y : env[1].x);
            const float gv = g_lds[prow][32 + c] + bf2f((unsigned short)(epk[2] >> (16 * e))) + (e ? env[2].y : env[2].x);
            const float ov = g_lds[prow][48 + c] + bf2f((unsigned short)(epk[3] >> (16 * e))) + (e ? env[3].y : env[3].x);
            float cc = e ? c1 : c0;
            const float cn = sigmoid_f(fv) * cc + sigmoid_f(iv) * tanh_f(gv);
            if (e) c1 = cn; else c0 = cn;
            hpack |= ((unsigned)f2bf(sigmoid_f(ov) * tanh_f(cn))) << (16 * e);
        }
        unsigned* hsp = (unsigned*)(hs + (size_t)t * (Bdim * Hdim) + (size_t)brow * Hdim + h0 + phc);
        if (fast)
            *hsp = hpack;                       // write-back, stays in XCD L2
        else
            __hip_atomic_store(hsp, hpack, __ATOMIC_RELAXED, __HIP_MEMORY_SCOPE_AGENT);

        if (t != Sdim - 1)
            tile_sync(bar, bi, (unsigned)(t + 2));
    }
}

// ---------------------------------------------------------------------------
// logits = hs[36096,512](bf16) * out_W^T(bf16) + out_b(fp32) -> fp32
// out[b][s][v], row m = s*256 + b.
// ---------------------------------------------------------------------------
__global__ __launch_bounds__(256) void gemm_logits(
    const unsigned short* __restrict__ A,
    const unsigned short* __restrict__ W,
    const float* __restrict__ bias,
    float* __restrict__ out)
{
    const int m0 = blockIdx.x * 128;
    const int n0 = blockIdx.y * 64;
    const int w    = threadIdx.x >> 6;
    const int l    = threadIdx.x & 63;
    const int lr   = l & 15;
    const int quad = l >> 4;

    const unsigned short* pa0 = A + (size_t)(m0 + w * 32 + lr) * Hdim + quad * 8;
    const unsigned short* pa1 = pa0 + (size_t)16 * Hdim;
    const unsigned short* pb[4];
#pragma unroll
    for (int nj = 0; nj < 4; ++nj) {
        int rb = n0 + nj * 16 + lr;
        rb = rb < Vdim ? rb : Vdim - 1;
        pb[nj] = W + (size_t)rb * Hdim + quad * 8;
    }

    f32x4 acc[2][4];
#pragma unroll
    for (int mi = 0; mi < 2; ++mi)
#pragma unroll
        for (int nj = 0; nj < 4; ++nj)
            acc[mi][nj] = (f32x4){0.f, 0.f, 0.f, 0.f};

    for (int k = 0; k < Hdim; k += 32) {
        bf16x8 a0 = *(const bf16x8*)(pa0 + k);
        bf16x8 a1 = *(const bf16x8*)(pa1 + k);
#pragma unroll
        for (int nj = 0; nj < 4; ++nj) {
            bf16x8 bb = *(const bf16x8*)(pb[nj] + k);
            acc[0][nj] = __builtin_amdgcn_mfma_f32_16x16x32_bf16(a0, bb, acc[0][nj], 0, 0, 0);
            acc[1][nj] = __builtin_amdgcn_mfma_f32_16x16x32_bf16(a1, bb, acc[1][nj], 0, 0, 0);
        }
    }

#pragma unroll
    for (int nj = 0; nj < 4; ++nj) {
        const int col = n0 + nj * 16 + lr;
        if (col >= Vdim) continue;
        const float bv = bias[col];
#pragma unroll
        for (int mi = 0; mi < 2; ++mi) {
            const int rowb = m0 + w * 32 + mi * 16 + quad * 4;
#pragma unroll
            for (int r = 0; r < 4; ++r) {
                const int row = rowb + r;            // row = s*256 + b
                const int s = row >> 8;
                const int b = row & 255;
                out[((size_t)b * Sdim + s) * Vdim + col] = acc[mi][nj][r] + bv;
            }
        }
    }
}

extern "C" void kernel_launch(void* const* d_in, const int* in_sizes, int n_in,
                              void* d_out, int out_size, void* d_ws, size_t ws_size,
                              hipStream_t stream) {
    const float* enc   = (const float*)d_in[0];
    const int*   tgt   = (const int*)d_in[1];
    const float* emb   = (const float*)d_in[2];
    const float* W_ih  = (const float*)d_in[3];
    const float* W_hh  = (const float*)d_in[4];
    const float* b_ih  = (const float*)d_in[5];
    const float* b_hh  = (const float*)d_in[6];
    // d_in[7..9]: attn_W / attn_b / v_w — dead code (softmax over 1 source pos)
    const float* out_W = (const float*)d_in[10];
    const float* out_b = (const float*)d_in[11];
    float* out = (float*)d_out;

    char* ws = (char*)d_ws;
    unsigned short* whh_bf   = (unsigned short*)ws;                     // 2,097,152 B
    unsigned short* outw_bf  = (unsigned short*)(ws + 2097152);         // 1,024,000 B
    unsigned short* emb_proj = (unsigned short*)(ws + 3121152);         // 4,096,000 B
    float*          enc_proj = (float*)(ws + 7217152);                  // 2,097,152 B
    unsigned short* hs       = (unsigned short*)(ws + 9314304);         // 36,962,304 B
    unsigned*       bar      = (unsigned*)(ws + 46276608);              // 4,096 B
    // total ws use = 46,280,704 B

    hipMemsetAsync(bar, 0, 4096, stream);   // barrier counters (re-poisoned each call)

    f32_to_bf16_4<<<dim3((262144 + 255) / 256), 256, 0, stream>>>(
        (const float4*)W_hh, (u16x4*)whh_bf, 262144);
    f32_to_bf16_4<<<dim3((128000 + 255) / 256), 256, 0, stream>>>(
        (const float4*)out_W, (u16x4*)outw_bf, 128000);

    // emb_proj = embedding @ W_ih[:, :E].T               (bf16, [1000,2048])
    gemm_bt_f32in<true><<<dim3(8, 32), 256, 0, stream>>>(
        emb, Edim, Vdim, W_ih, 2 * Edim, emb_proj, G4H, nullptr, nullptr, Edim);
    // enc_proj = encoder_output @ W_ih[:, E:].T + b_ih + b_hh   (fp32, [256,2048])
    gemm_bt_f32in<false><<<dim3(2, 32), 256, 0, stream>>>(
        enc, Edim, Bdim, W_ih + Edim, 2 * Edim, enc_proj, G4H, b_ih, b_hh, Edim);
    // weights-stationary scan: 256 blocks = 8 XCD-local tiles x 32 h-tiles
    lstm_scan<<<dim3(256), 256, 0, stream>>>(whh_bf, emb_proj, enc_proj, tgt, hs, bar);
    // logits = hs @ out_W.T + out_b   (fp32 out)
    gemm_logits<<<dim3(282, 16), 256, 0, stream>>>(hs, outw_bf, out_b, out);
}

// Round 5
// 1423.792 us; speedup vs baseline: 4.4907x; 1.0186x over previous
//
#include <hip/hip_runtime.h>

typedef __attribute__((ext_vector_type(8))) short bf16x8;
typedef __attribute__((ext_vector_type(4))) float f32x4;
typedef __attribute__((ext_vector_type(4))) unsigned short u16x4;

#define Bdim 256
#define Sdim 141
#define Vdim 1000
#define Edim 256
#define Hdim 512
#define G4H  2048

__device__ __forceinline__ float bf2f(unsigned short u) {
    union { unsigned int i; float f; } x; x.i = ((unsigned int)u) << 16; return x.f;
}
__device__ __forceinline__ unsigned short f2bf(float f) {
    union { float f; unsigned int i; } x; x.f = f;
    unsigned int i = x.i;
    return (unsigned short)((i + 0x7FFFu + ((i >> 16) & 1u)) >> 16);  // RNE
}
__device__ __forceinline__ float sigmoid_f(float x) { return 1.f / (1.f + __expf(-x)); }
__device__ __forceinline__ float tanh_f(float x)    { return 1.f - 2.f / (__expf(2.f * x) + 1.f); }

__device__ __forceinline__ bf16x8 cvt8(const float* p) {
    const float4 v0 = ((const float4*)p)[0];
    const float4 v1 = ((const float4*)p)[1];
    bf16x8 r;
    r[0] = (short)f2bf(v0.x); r[1] = (short)f2bf(v0.y);
    r[2] = (short)f2bf(v0.z); r[3] = (short)f2bf(v0.w);
    r[4] = (short)f2bf(v1.x); r[5] = (short)f2bf(v1.y);
    r[6] = (short)f2bf(v1.z); r[7] = (short)f2bf(v1.w);
    return r;
}

// ---------------------------------------------------------------------------
// Bulk fp32 -> bf16 (RNE), vectorized x4.
// ---------------------------------------------------------------------------
__global__ __launch_bounds__(256) void f32_to_bf16_4(
    const float4* __restrict__ src, u16x4* __restrict__ dst, int n4)
{
    const int i = blockIdx.x * 256 + threadIdx.x;
    if (i < n4) {
        const float4 v = src[i];
        u16x4 r;
        r[0] = f2bf(v.x); r[1] = f2bf(v.y); r[2] = f2bf(v.z); r[3] = f2bf(v.w);
        dst[i] = r;
    }
}

// ---------------------------------------------------------------------------
// C = A * B^T (+bias), fp32 inputs converted inline to bf16 for MFMA.
// Tile 128x64, 4 waves. Layouts verified (m89/m92).
// ---------------------------------------------------------------------------
template <bool BF16OUT>
__global__ __launch_bounds__(256) void gemm_bt_f32in(
    const float* __restrict__ A, int lda, int M,
    const float* __restrict__ Bw, int ldb,
    void* __restrict__ Cv, int ldc,
    const float* __restrict__ bias0,
    const float* __restrict__ bias1,
    int K)
{
    const int m0 = blockIdx.x * 128;
    const int n0 = blockIdx.y * 64;
    const int w    = threadIdx.x >> 6;
    const int l    = threadIdx.x & 63;
    const int lr   = l & 15;
    const int quad = l >> 4;

    int ra0 = m0 + w * 32 + lr;
    int ra1 = ra0 + 16;
    ra0 = ra0 < M ? ra0 : M - 1;
    ra1 = ra1 < M ? ra1 : M - 1;
    const float* pa0 = A + (size_t)ra0 * lda + quad * 8;
    const float* pa1 = A + (size_t)ra1 * lda + quad * 8;
    const float* pb[4];
#pragma unroll
    for (int nj = 0; nj < 4; ++nj)
        pb[nj] = Bw + (size_t)(n0 + nj * 16 + lr) * ldb + quad * 8;

    f32x4 acc[2][4];
#pragma unroll
    for (int mi = 0; mi < 2; ++mi)
#pragma unroll
        for (int nj = 0; nj < 4; ++nj)
            acc[mi][nj] = (f32x4){0.f, 0.f, 0.f, 0.f};

    for (int k = 0; k < K; k += 32) {
        bf16x8 a0 = cvt8(pa0 + k);
        bf16x8 a1 = cvt8(pa1 + k);
#pragma unroll
        for (int nj = 0; nj < 4; ++nj) {
            bf16x8 bb = cvt8(pb[nj] + k);
            acc[0][nj] = __builtin_amdgcn_mfma_f32_16x16x32_bf16(a0, bb, acc[0][nj], 0, 0, 0);
            acc[1][nj] = __builtin_amdgcn_mfma_f32_16x16x32_bf16(a1, bb, acc[1][nj], 0, 0, 0);
        }
    }

#pragma unroll
    for (int nj = 0; nj < 4; ++nj) {
        const int col = n0 + nj * 16 + lr;
        float bv = 0.f;
        if (bias0) bv += bias0[col];
        if (bias1) bv += bias1[col];
#pragma unroll
        for (int mi = 0; mi < 2; ++mi) {
            const int row = m0 + w * 32 + mi * 16 + quad * 4;
#pragma unroll
            for (int r = 0; r < 4; ++r) {
                if (row + r < M) {
                    const float v = acc[mi][nj][r] + bv;
                    if (BF16OUT)
                        ((unsigned short*)Cv)[(size_t)(row + r) * ldc + col] = f2bf(v);
                    else
                        ((float*)Cv)[(size_t)(row + r) * ldc + col] = v;
                }
            }
        }
    }
}

// ---------------------------------------------------------------------------
// Per-tile barrier, 32 blocks, monotonic counter, RMW-poll.
// Arrival: fetch_add(1) (count in low 16 bits; max 142*32=4544 < 65536).
// Poll: fetch_add(0x10000) — non-idempotent RMW, so it always executes at
// the L2/coherent serialization point (never satisfied from stale L1) and
// cannot be rewritten into a cacheable load; bit-16 adds never carry into
// the low 16 bits (low bits are always preserved by +0x10000).
// Release condition: (ctr & 0xFFFF) >= target*32.
//
// SCOPE DISCIPLINE (the round-4 failure hypothesis): a counter line is owned
// by exactly ONE scope for its lifetime. Agent-scope ops execute at the
// coherent point (bypassing the XCD L2); workgroup-scope ops execute in the
// local L2. Mixing them on one line can leave the local L2 with a copy that
// never reflects the agent-side updates -> infinite spin. Therefore:
//   - AGENT counter   at bar[256 + bi*32]: init barrier + slow-path barriers.
//   - FAST counter    at bar[768 + bi*32]: workgroup-scope RMWs ONLY. Its
//     initial 0 comes from the memset; a cached zero equals the true zero,
//     so any fill source is correct, and thereafter the local L2 is the
//     single serialization point (all 32 blocks proven same-XCD).
// Guard: 2^16 polls (~8 ms/barrier worst case) — a logic bug yields a
// finite wrong answer, never a queue-timeout container kill.
// Ordering: entry __syncthreads drains vmcnt(0) per wave, so all h stores
// are acked (local L2 fast / coherent point slow) before thread 0's arrival
// RMW. Exit workgroup-acquire fence = compiler ordering only.
// ---------------------------------------------------------------------------
__device__ __forceinline__ void sync_agent(unsigned* bar, int bi, unsigned target) {
    __syncthreads();
    if (threadIdx.x == 0) {
        unsigned* ctr = bar + 256 + bi * 32;
        const unsigned goal = target * 32u;
        __hip_atomic_fetch_add(ctr, 1u, __ATOMIC_RELAXED, __HIP_MEMORY_SCOPE_AGENT);
        int guard = 0;
        while ((__hip_atomic_fetch_add(ctr, 0x10000u, __ATOMIC_RELAXED,
                                       __HIP_MEMORY_SCOPE_AGENT) & 0xFFFFu) < goal
               && ++guard < (1 << 16))
            __builtin_amdgcn_s_sleep(1);
        __builtin_amdgcn_fence(__ATOMIC_ACQUIRE, "workgroup");
    }
    __syncthreads();
}

__device__ __forceinline__ void sync_fast(unsigned* bar, int bi, unsigned target) {
    __syncthreads();
    if (threadIdx.x == 0) {
        unsigned* ctr = bar + 768 + bi * 32;     // workgroup-scope-only line
        const unsigned goal = target * 32u;
        __hip_atomic_fetch_add(ctr, 1u, __ATOMIC_RELAXED, __HIP_MEMORY_SCOPE_WORKGROUP);
        int guard = 0;
        while ((__hip_atomic_fetch_add(ctr, 0x10000u, __ATOMIC_RELAXED,
                                       __HIP_MEMORY_SCOPE_WORKGROUP) & 0xFFFFu) < goal
               && ++guard < (1 << 16))
            __builtin_amdgcn_s_sleep(1);
        __builtin_amdgcn_fence(__ATOMIC_ACQUIRE, "workgroup");
    }
    __syncthreads();
}

// ---------------------------------------------------------------------------
// Weights-stationary LSTM scan, XCD-local h exchange.
// 256 blocks = 8 batch-tiles(32 rows) x 32 h-tiles(16 h-cols). Tile bi =
// blk&7: with round-robin dispatch all 32 blocks of a tile land on XCD bi,
// so the h exchange stays inside one L2 (plain write-back stores + plain
// reads) and the barrier runs on XCD-local L2 atomics (sync_fast).
// CORRECTNESS GUARD: each block ORs its HW_REG_XCC_ID into a per-tile mask;
// tiles whose blocks do NOT share an XCD fall back to write-through agent
// stores + agent-scope barrier (round-2-proven). Wrong mapping degrades
// speed, never correctness.
// Latency hiding: enc_proj slice is time-invariant -> registers, once.
// emb_proj gather for step t+1 is issued at the TOP of step t, so its
// vmcnt drain at the g_lds __syncthreads is covered by the MFMA phase and
// the value is long-resident when consumed at t+1.
// ---------------------------------------------------------------------------
__global__ __launch_bounds__(256) void lstm_scan(
    const unsigned short* __restrict__ Whh,      // [2048,512] bf16
    const unsigned short* __restrict__ emb_proj, // [1000,2048] bf16
    const float* __restrict__ enc_proj,          // [256,2048] fp32 (biases folded)
    const int* __restrict__ tgt,                 // [256,141]
    unsigned short* __restrict__ hs,             // [141,256,512] bf16 (h_1..h_141)
    unsigned* __restrict__ bar)
{
    const int blk = blockIdx.x;
    const int bi  = blk & 7;         // batch tile 0..7 == XCD (round-robin)
    const int ht  = blk >> 3;        // h tile 0..31 (16 cols)
    const int r0  = bi * 32;
    const int h0  = ht * 16;
    const int tid = threadIdx.x;
    const int nf   = tid >> 6;       // wave = gate 0..3 (i,f,g,o)
    const int l    = tid & 63;
    const int lr   = l & 15;
    const int quad = l >> 4;

    __shared__ unsigned short w_lds[4096 * 8];   // 64 KB fragment-major
    __shared__ float g_lds[32][67];              // gates [row][g*16+c]

    // Stage W slice. Unit u=(g,k16,quad,lr): 8 bf16 of W row g*512+h0+lr at
    // cols k16*32+quad*8. Flat unit index == u, so the MFMA-time read addr
    // for wave nf, lane l is ((nf*16+k16)*64 + l) -> conflict-free b128.
    for (int u = tid; u < 4096; u += 256) {
        const int ulr = u & 15;
        const int uq  = (u >> 4) & 3;
        const int uk  = (u >> 6) & 15;
        const int ug  = u >> 10;
        *(bf16x8*)&w_lds[u * 8] =
            *(const bf16x8*)(Whh + (size_t)(ug * Hdim + h0 + ulr) * Hdim + uk * 32 + uq * 8);
    }

    // XCD-placement guard: OR my physical XCD into the tile's bitmask.
    int xcc;
    asm volatile("s_getreg_b32 %0, hwreg(HW_REG_XCC_ID)" : "=s"(xcc));
    if (tid == 0) {
        __hip_atomic_fetch_or(bar + 512 + bi * 32, 1u << (xcc & 7),
                              __ATOMIC_RELAXED, __HIP_MEMORY_SCOPE_AGENT);
        asm volatile("s_waitcnt vmcnt(0)" ::: "memory");   // OR acked before arrival
    }
    sync_agent(bar, bi, 1u);                    // agent-scope init; covers W staging
    const unsigned fl = __hip_atomic_load(bar + 512 + bi * 32,
                              __ATOMIC_RELAXED, __HIP_MEMORY_SCOPE_AGENT);
    const bool fast = (fl & (fl - 1u)) == 0u;   // all 32 blocks on one XCD

    const int prow = tid & 31;           // pointwise: local batch row
    const int phc  = (tid >> 5) * 2;     // pointwise: 2 of my 16 h-cols
    const int brow = r0 + prow;

    const int* tokp = tgt + (size_t)brow * Sdim;

    // enc_proj slice is TIME-INVARIANT: load once into registers.
    const float* encp = enc_proj + (size_t)brow * G4H + h0 + phc;
    float2 env[4];
#pragma unroll
    for (int g = 0; g < 4; ++g)
        env[g] = *(const float2*)(encp + g * Hdim);

    // emb gather for t=0 (exposed once, trivial).
    unsigned epk[4];
    {
        const unsigned short* embp = emb_proj + (size_t)tokp[0] * G4H + h0 + phc;
#pragma unroll
        for (int g = 0; g < 4; ++g)
            epk[g] = *(const unsigned*)(embp + g * Hdim);
    }

    const size_t arow0 = (size_t)(r0 + lr) * Hdim + quad * 8;
    const size_t arow1 = (size_t)(r0 + 16 + lr) * Hdim + quad * 8;
    const unsigned short* wlp = w_lds + (size_t)nf * 1024 * 8;

    float c0 = 0.f, c1 = 0.f;

    for (int t = 0; t < Sdim; ++t) {
        // --- one-step-ahead emb gather (for t+1): issued before the MFMA
        //     phase so its drain at the g_lds sync is MFMA-covered and it is
        //     register-resident when consumed next step.
        const int tn = tokp[t + 1 < Sdim ? t + 1 : t];
        unsigned epkn[4];
        {
            const unsigned short* embn = emb_proj + (size_t)tn * G4H + h0 + phc;
#pragma unroll
            for (int g = 0; g < 4; ++g)
                epkn[g] = *(const unsigned*)(embn + g * Hdim);
        }

        f32x4 acc0 = (f32x4){0.f, 0.f, 0.f, 0.f};
        f32x4 acc1 = (f32x4){0.f, 0.f, 0.f, 0.f};
        if (t > 0) {
            const unsigned short* hprev = hs + (size_t)(t - 1) * (Bdim * Hdim);
#pragma unroll
            for (int k16 = 0; k16 < 16; ++k16) {
                bf16x8 a0 = *(const bf16x8*)(hprev + arow0 + k16 * 32);
                bf16x8 a1 = *(const bf16x8*)(hprev + arow1 + k16 * 32);
                bf16x8 bb = *(const bf16x8*)&wlp[(k16 * 64 + l) * 8];
                acc0 = __builtin_amdgcn_mfma_f32_16x16x32_bf16(a0, bb, acc0, 0, 0, 0);
                acc1 = __builtin_amdgcn_mfma_f32_16x16x32_bf16(a1, bb, acc1, 0, 0, 0);
            }
        }
        // C/D: col=lane&15 -> gate-row nf*16+lr; row = quad*4+reg (+16 for acc1)
#pragma unroll
        for (int r = 0; r < 4; ++r) {
            g_lds[quad * 4 + r][nf * 16 + lr]      = acc0[r];
            g_lds[16 + quad * 4 + r][nf * 16 + lr] = acc1[r];
        }
        __syncthreads();

        unsigned hpack = 0;
#pragma unroll
        for (int e = 0; e < 2; ++e) {
            const int c = phc + e;
            const float iv = g_lds[prow][c]      + bf2f((unsigned short)(epk[0] >> (16 * e))) + (e ? env[0].y : env[0].x);
            const float fv = g_lds[prow][16 + c] + bf2f((unsigned short)(epk[1] >> (16 * e))) + (e ? env[1].y : env[1].x);
            const float gv = g_lds[prow][32 + c] + bf2f((unsigned short)(epk[2] >> (16 * e))) + (e ? env[2].y : env[2].x);
            const float ov = g_lds[prow][48 + c] + bf2f((unsigned short)(epk[3] >> (16 * e))) + (e ? env[3].y : env[3].x);
            float cc = e ? c1 : c0;
            const float cn = sigmoid_f(fv) * cc + sigmoid_f(iv) * tanh_f(gv);
            if (e) c1 = cn; else c0 = cn;
            hpack |= ((unsigned)f2bf(sigmoid_f(ov) * tanh_f(cn))) << (16 * e);
        }
        unsigned* hsp = (unsigned*)(hs + (size_t)t * (Bdim * Hdim) + (size_t)brow * Hdim + h0 + phc);
        if (fast)
            *hsp = hpack;                       // write-back, stays in XCD L2
        else
            __hip_atomic_store(hsp, hpack, __ATOMIC_RELAXED, __HIP_MEMORY_SCOPE_AGENT);

        if (t != Sdim - 1) {
            if (fast) sync_fast(bar, bi, (unsigned)(t + 1));   // fast ctr starts at 0
            else      sync_agent(bar, bi, (unsigned)(t + 2));  // agent ctr holds init's 32
        }

#pragma unroll
        for (int g = 0; g < 4; ++g)
            epk[g] = epkn[g];                   // long-returned; no stall here
    }
}

// ---------------------------------------------------------------------------
// logits = hs[36096,512](bf16) * out_W^T(bf16) + out_b(fp32) -> fp32
// out[b][s][v], row m = s*256 + b.
// ---------------------------------------------------------------------------
__global__ __launch_bounds__(256) void gemm_logits(
    const unsigned short* __restrict__ A,
    const unsigned short* __restrict__ W,
    const float* __restrict__ bias,
    float* __restrict__ out)
{
    const int m0 = blockIdx.x * 128;
    const int n0 = blockIdx.y * 64;
    const int w    = threadIdx.x >> 6;
    const int l    = threadIdx.x & 63;
    const int lr   = l & 15;
    const int quad = l >> 4;

    const unsigned short* pa0 = A + (size_t)(m0 + w * 32 + lr) * Hdim + quad * 8;
    const unsigned short* pa1 = pa0 + (size_t)16 * Hdim;
    const unsigned short* pb[4];
#pragma unroll
    for (int nj = 0; nj < 4; ++nj) {
        int rb = n0 + nj * 16 + lr;
        rb = rb < Vdim ? rb : Vdim - 1;
        pb[nj] = W + (size_t)rb * Hdim + quad * 8;
    }

    f32x4 acc[2][4];
#pragma unroll
    for (int mi = 0; mi < 2; ++mi)
#pragma unroll
        for (int nj = 0; nj < 4; ++nj)
            acc[mi][nj] = (f32x4){0.f, 0.f, 0.f, 0.f};

    for (int k = 0; k < Hdim; k += 32) {
        bf16x8 a0 = *(const bf16x8*)(pa0 + k);
        bf16x8 a1 = *(const bf16x8*)(pa1 + k);
#pragma unroll
        for (int nj = 0; nj < 4; ++nj) {
            bf16x8 bb = *(const bf16x8*)(pb[nj] + k);
            acc[0][nj] = __builtin_amdgcn_mfma_f32_16x16x32_bf16(a0, bb, acc[0][nj], 0, 0, 0);
            acc[1][nj] = __builtin_amdgcn_mfma_f32_16x16x32_bf16(a1, bb, acc[1][nj], 0, 0, 0);
        }
    }

#pragma unroll
    for (int nj = 0; nj < 4; ++nj) {
        const int col = n0 + nj * 16 + lr;
        if (col >= Vdim) continue;
        const float bv = bias[col];
#pragma unroll
        for (int mi = 0; mi < 2; ++mi) {
            const int rowb = m0 + w * 32 + mi * 16 + quad * 4;
#pragma unroll
            for (int r = 0; r < 4; ++r) {
                const int row = rowb + r;            // row = s*256 + b
                const int s = row >> 8;
                const int b = row & 255;
                out[((size_t)b * Sdim + s) * Vdim + col] = acc[mi][nj][r] + bv;
            }
        }
    }
}

extern "C" void kernel_launch(void* const* d_in, const int* in_sizes, int n_in,
                              void* d_out, int out_size, void* d_ws, size_t ws_size,
                              hipStream_t stream) {
    const float* enc   = (const float*)d_in[0];
    const int*   tgt   = (const int*)d_in[1];
    const float* emb   = (const float*)d_in[2];
    const float* W_ih  = (const float*)d_in[3];
    const float* W_hh  = (const float*)d_in[4];
    const float* b_ih  = (const float*)d_in[5];
    const float* b_hh  = (const float*)d_in[6];
    // d_in[7..9]: attn_W / attn_b / v_w — dead code (softmax over 1 source pos)
    const float* out_W = (const float*)d_in[10];
    const float* out_b = (const float*)d_in[11];
    float* out = (float*)d_out;

    char* ws = (char*)d_ws;
    unsigned short* whh_bf   = (unsigned short*)ws;                     // 2,097,152 B
    unsigned short* outw_bf  = (unsigned short*)(ws + 2097152);         // 1,024,000 B
    unsigned short* emb_proj = (unsigned short*)(ws + 3121152);         // 4,096,000 B
    float*          enc_proj = (float*)(ws + 7217152);                  // 2,097,152 B
    unsigned short* hs       = (unsigned short*)(ws + 9314304);         // 36,962,304 B
    unsigned*       bar      = (unsigned*)(ws + 46276608);              // 4,096 B
    // total ws use = 46,280,704 B

    hipMemsetAsync(bar, 0, 4096, stream);   // barrier counters (re-poisoned each call)

    f32_to_bf16_4<<<dim3((262144 + 255) / 256), 256, 0, stream>>>(
        (const float4*)W_hh, (u16x4*)whh_bf, 262144);
    f32_to_bf16_4<<<dim3((128000 + 255) / 256), 256, 0, stream>>>(
        (const float4*)out_W, (u16x4*)outw_bf, 128000);

    // emb_proj = embedding @ W_ih[:, :E].T               (bf16, [1000,2048])
    gemm_bt_f32in<true><<<dim3(8, 32), 256, 0, stream>>>(
        emb, Edim, Vdim, W_ih, 2 * Edim, emb_proj, G4H, nullptr, nullptr, Edim);
    // enc_proj = encoder_output @ W_ih[:, E:].T + b_ih + b_hh   (fp32, [256,2048])
    gemm_bt_f32in<false><<<dim3(2, 32), 256, 0, stream>>>(
        enc, Edim, Bdim, W_ih + Edim, 2 * Edim, enc_proj, G4H, b_ih, b_hh, Edim);
    // weights-stationary scan: 256 blocks = 8 XCD-local tiles x 32 h-tiles
    lstm_scan<<<dim3(256), 256, 0, stream>>>(whh_bf, emb_proj, enc_proj, tgt, hs, bar);
    // logits = hs @ out_W.T + out_b   (fp32 out)
    gemm_logits<<<dim3(282, 16), 256, 0, stream>>>(hs, outw_bf, out_b, out);
}

// Round 7
// 1154.471 us; speedup vs baseline: 5.5383x; 1.2333x over previous
//
#include <hip/hip_runtime.h>

typedef __attribute__((ext_vector_type(8))) short bf16x8;
typedef __attribute__((ext_vector_type(4))) float f32x4;
typedef __attribute__((ext_vector_type(4))) unsigned short u16x4;

#define Bdim 256
#define Sdim 141
#define Vdim 1000
#define Edim 256
#define Hdim 512
#define G4H  2048

__device__ __forceinline__ float bf2f(unsigned short u) {
    union { unsigned int i; float f; } x; x.i = ((unsigned int)u) << 16; return x.f;
}
__device__ __forceinline__ unsigned short f2bf(float f) {
    union { float f; unsigned int i; } x; x.f = f;
    unsigned int i = x.i;
    return (unsigned short)((i + 0x7FFFu + ((i >> 16) & 1u)) >> 16);  // RNE
}
__device__ __forceinline__ float sigmoid_f(float x) { return 1.f / (1.f + __expf(-x)); }
__device__ __forceinline__ float tanh_f(float x)    { return 1.f - 2.f / (__expf(2.f * x) + 1.f); }

__device__ __forceinline__ bf16x8 cvt8(const float* p) {
    const float4 v0 = ((const float4*)p)[0];
    const float4 v1 = ((const float4*)p)[1];
    bf16x8 r;
    r[0] = (short)f2bf(v0.x); r[1] = (short)f2bf(v0.y);
    r[2] = (short)f2bf(v0.z); r[3] = (short)f2bf(v0.w);
    r[4] = (short)f2bf(v1.x); r[5] = (short)f2bf(v1.y);
    r[6] = (short)f2bf(v1.z); r[7] = (short)f2bf(v1.w);
    return r;
}

// ---------------------------------------------------------------------------
// Bulk fp32 -> bf16 (RNE), vectorized x4.
// ---------------------------------------------------------------------------
__global__ __launch_bounds__(256) void f32_to_bf16_4(
    const float4* __restrict__ src, u16x4* __restrict__ dst, int n4)
{
    const int i = blockIdx.x * 256 + threadIdx.x;
    if (i < n4) {
        const float4 v = src[i];
        u16x4 r;
        r[0] = f2bf(v.x); r[1] = f2bf(v.y); r[2] = f2bf(v.z); r[3] = f2bf(v.w);
        dst[i] = r;
    }
}

// ---------------------------------------------------------------------------
// C = A * B^T (+bias), fp32 inputs converted inline to bf16 for MFMA.
// Tile 128x64, 4 waves. Layouts verified (m89/m92).
// ---------------------------------------------------------------------------
template <bool BF16OUT>
__global__ __launch_bounds__(256) void gemm_bt_f32in(
    const float* __restrict__ A, int lda, int M,
    const float* __restrict__ Bw, int ldb,
    void* __restrict__ Cv, int ldc,
    const float* __restrict__ bias0,
    const float* __restrict__ bias1,
    int K)
{
    const int m0 = blockIdx.x * 128;
    const int n0 = blockIdx.y * 64;
    const int w    = threadIdx.x >> 6;
    const int l    = threadIdx.x & 63;
    const int lr   = l & 15;
    const int quad = l >> 4;

    int ra0 = m0 + w * 32 + lr;
    int ra1 = ra0 + 16;
    ra0 = ra0 < M ? ra0 : M - 1;
    ra1 = ra1 < M ? ra1 : M - 1;
    const float* pa0 = A + (size_t)ra0 * lda + quad * 8;
    const float* pa1 = A + (size_t)ra1 * lda + quad * 8;
    const float* pb[4];
#pragma unroll
    for (int nj = 0; nj < 4; ++nj)
        pb[nj] = Bw + (size_t)(n0 + nj * 16 + lr) * ldb + quad * 8;

    f32x4 acc[2][4];
#pragma unroll
    for (int mi = 0; mi < 2; ++mi)
#pragma unroll
        for (int nj = 0; nj < 4; ++nj)
            acc[mi][nj] = (f32x4){0.f, 0.f, 0.f, 0.f};

    for (int k = 0; k < K; k += 32) {
        bf16x8 a0 = cvt8(pa0 + k);
        bf16x8 a1 = cvt8(pa1 + k);
#pragma unroll
        for (int nj = 0; nj < 4; ++nj) {
            bf16x8 bb = cvt8(pb[nj] + k);
            acc[0][nj] = __builtin_amdgcn_mfma_f32_16x16x32_bf16(a0, bb, acc[0][nj], 0, 0, 0);
            acc[1][nj] = __builtin_amdgcn_mfma_f32_16x16x32_bf16(a1, bb, acc[1][nj], 0, 0, 0);
        }
    }

#pragma unroll
    for (int nj = 0; nj < 4; ++nj) {
        const int col = n0 + nj * 16 + lr;
        float bv = 0.f;
        if (bias0) bv += bias0[col];
        if (bias1) bv += bias1[col];
#pragma unroll
        for (int mi = 0; mi < 2; ++mi) {
            const int row = m0 + w * 32 + mi * 16 + quad * 4;
#pragma unroll
            for (int r = 0; r < 4; ++r) {
                if (row + r < M) {
                    const float v = acc[mi][nj][r] + bv;
                    if (BF16OUT)
                        ((unsigned short*)Cv)[(size_t)(row + r) * ldc + col] = f2bf(v);
                    else
                        ((float*)Cv)[(size_t)(row + r) * ldc + col] = v;
                }
            }
        }
    }
}

// ---------------------------------------------------------------------------
// Per-tile barrier, 16 blocks, monotonic counter, RMW-poll.
// Arrival: fetch_add(1) (count in low 16 bits; max 142*16=2272 < 65536).
// Poll: fetch_add(0x10000) — non-idempotent RMW: always executes at the
// L2/coherent serialization point (immune to stale L1, cannot be rewritten
// into a cacheable load); bit-16 adds never touch the low 16 bits.
// Release: (ctr & 0xFFFF) >= target*16.
//
// SCOPE DISCIPLINE (one line = one scope for its lifetime):
//   - AGENT line  bar[bi*32 .. +31]: word0 = agent counter (init + slow
//     path), word16 = XCD mask. Agent RMWs execute at the coherent point.
//   - FAST line   bar[512 + bi*32]: workgroup-scope RMWs ONLY (local-L2
//     serialization; initial 0 from memset is scope-neutral).
// Guard: 2^16 polls (~ms) — a logic bug yields a finite wrong answer,
// never a queue-timeout container kill.
// Ordering: entry __syncthreads drains vmcnt(0) per wave -> all h stores
// acked (local L2 fast / coherent point slow) before the arrival RMW.
// Exit workgroup-acquire fence = compiler ordering only.
// ---------------------------------------------------------------------------
__device__ __forceinline__ void sync_agent(unsigned* bar, int bi, unsigned target) {
    __syncthreads();
    if (threadIdx.x == 0) {
        unsigned* ctr = bar + bi * 32;
        const unsigned goal = target * 16u;
        __hip_atomic_fetch_add(ctr, 1u, __ATOMIC_RELAXED, __HIP_MEMORY_SCOPE_AGENT);
        int guard = 0;
        while ((__hip_atomic_fetch_add(ctr, 0x10000u, __ATOMIC_RELAXED,
                                       __HIP_MEMORY_SCOPE_AGENT) & 0xFFFFu) < goal
               && ++guard < (1 << 16))
            __builtin_amdgcn_s_sleep(1);
        __builtin_amdgcn_fence(__ATOMIC_ACQUIRE, "workgroup");
    }
    __syncthreads();
}

__device__ __forceinline__ void sync_fast(unsigned* bar, int bi, unsigned target) {
    __syncthreads();
    if (threadIdx.x == 0) {
        unsigned* ctr = bar + 512 + bi * 32;     // workgroup-scope-only line
        const unsigned goal = target * 16u;
        __hip_atomic_fetch_add(ctr, 1u, __ATOMIC_RELAXED, __HIP_MEMORY_SCOPE_WORKGROUP);
        int guard = 0;
        while ((__hip_atomic_fetch_add(ctr, 0x10000u, __ATOMIC_RELAXED,
                                       __HIP_MEMORY_SCOPE_WORKGROUP) & 0xFFFFu) < goal
               && ++guard < (1 << 16))
            __builtin_amdgcn_s_sleep(1);
        __builtin_amdgcn_fence(__ATOMIC_ACQUIRE, "workgroup");
    }
    __syncthreads();
}

// ---------------------------------------------------------------------------
// Weights-stationary LSTM scan, XCD-local h exchange, 16-block sync domains.
// 256 blocks = 16 tiles x 16 h-blocks. Tile bi = (blk&7)*2 + ((blk>>3)&1):
// with round-robin dispatch (blockIdx%8 = XCD) all 16 blocks of a tile sit
// on XCD blk&7 -> h exchange and barrier stay in one L2.
// Tile = 16 batch rows; block = 32 h-cols (W slice 4g x 32c x 512k = 128 KB
// LDS, fragment-major, conflict-free ds_read_b128). 512 threads = 8 waves
// (2/SIMD for latency overlap); wave w covers gate w>>1, col-half w&1 ->
// one 16-MFMA dependent chain per wave; all waves read the SAME 16 h-rows
// (16 KB panel, L1-resident after first wave).
// g_lds column layout: subtile s = gate*2+colhalf at cols [s*16, s*16+16),
// so gate g / local col phc (0..31) sits at column g*32 + phc  (phc =
// (phc>>4)*16 + (phc&15) identically).   <-- R6 bug was here: it read
// g*32 + (phc>>4)*32 + (phc&15), scrambling gates for phc>=16.
// CORRECTNESS GUARD: per-tile XCD mask from HW_REG_XCC_ID; non-co-resident
// tiles fall back to write-through agent h stores + agent barrier
// (round-2-proven). Wrong mapping degrades speed, never correctness.
// enc_proj slice: registers, once. emb gather: one step ahead.
// ---------------------------------------------------------------------------
__global__ __launch_bounds__(512) void lstm_scan(
    const unsigned short* __restrict__ Whh,      // [2048,512] bf16
    const unsigned short* __restrict__ emb_proj, // [1000,2048] bf16
    const float* __restrict__ enc_proj,          // [256,2048] fp32 (biases folded)
    const int* __restrict__ tgt,                 // [256,141]
    unsigned short* __restrict__ hs,             // [141,256,512] bf16 (h_1..h_141)
    unsigned* __restrict__ bar)
{
    const int blk = blockIdx.x;
    const int bi  = (blk & 7) * 2 + ((blk >> 3) & 1);  // tile 0..15 (one XCD)
    const int ht  = blk >> 4;        // h block 0..15 (32 cols)
    const int r0  = bi * 16;
    const int h0  = ht * 32;
    const int tid = threadIdx.x;
    const int w    = tid >> 6;       // wave 0..7: gate w>>1, col-half w&1
    const int l    = tid & 63;
    const int lr   = l & 15;
    const int quad = l >> 4;

    __shared__ unsigned short w_lds[8192 * 8];   // 128 KB fragment-major
    __shared__ float g_lds[16][132];             // gates [row][s*16+lr]

    // Stage W slice. Unit u=(s,k16,quad,lr), s = gate*2+colhalf: 8 bf16 of
    // W row (s>>1)*512 + h0 + (s&1)*16 + lr at cols k16*32+quad*8. Flat unit
    // index == u, so wave w's read addr at k16 is ((w*16+k16)*64 + l) * 8
    // -> conflict-free ds_read_b128.
    for (int u = tid; u < 8192; u += 512) {
        const int ulr = u & 15;
        const int uq  = (u >> 4) & 3;
        const int uk  = (u >> 6) & 15;
        const int us  = u >> 10;
        const int grow = (us >> 1) * Hdim + h0 + (us & 1) * 16 + ulr;
        *(bf16x8*)&w_lds[u * 8] =
            *(const bf16x8*)(Whh + (size_t)grow * Hdim + uk * 32 + uq * 8);
    }

    // XCD-placement guard: OR my physical XCD into the tile's mask (word 16
    // of the tile's agent-owned line).
    int xcc;
    asm volatile("s_getreg_b32 %0, hwreg(HW_REG_XCC_ID)" : "=s"(xcc));
    if (tid == 0) {
        __hip_atomic_fetch_or(bar + bi * 32 + 16, 1u << (xcc & 7),
                              __ATOMIC_RELAXED, __HIP_MEMORY_SCOPE_AGENT);
        asm volatile("s_waitcnt vmcnt(0)" ::: "memory");   // OR acked before arrival
    }
    sync_agent(bar, bi, 1u);                    // agent-scope init; covers W staging
    const unsigned fl = __hip_atomic_load(bar + bi * 32 + 16,
                              __ATOMIC_RELAXED, __HIP_MEMORY_SCOPE_AGENT);
    const bool fast = (fl & (fl - 1u)) == 0u;   // all 16 blocks on one XCD

    const int prow = tid >> 5;           // pointwise: local batch row 0..15
    const int phc  = tid & 31;           // pointwise: 1 of my 32 h-cols
    const int brow = r0 + prow;

    const int* tokp = tgt + (size_t)brow * Sdim;

    // enc_proj slice is TIME-INVARIANT: registers, once.
    const float* encp = enc_proj + (size_t)brow * G4H + h0 + phc;
    float env[4];
#pragma unroll
    for (int g = 0; g < 4; ++g)
        env[g] = encp[g * Hdim];

    // emb gather for t=0 (exposed once, trivial).
    unsigned short epk[4];
    {
        const unsigned short* embp = emb_proj + (size_t)tokp[0] * G4H + h0 + phc;
#pragma unroll
        for (int g = 0; g < 4; ++g)
            epk[g] = embp[g * Hdim];
    }

    const size_t arow = (size_t)(r0 + lr) * Hdim + quad * 8;
    const unsigned short* wlp = w_lds + (size_t)w * 1024 * 8;

    float c0 = 0.f;

    for (int t = 0; t < Sdim; ++t) {
        // one-step-ahead emb gather (for t+1): drain at the g_lds sync is
        // covered by the MFMA phase; register-resident when consumed.
        const int tn = tokp[t + 1 < Sdim ? t + 1 : t];
        unsigned short epkn[4];
        {
            const unsigned short* embn = emb_proj + (size_t)tn * G4H + h0 + phc;
#pragma unroll
            for (int g = 0; g < 4; ++g)
                epkn[g] = embn[g * Hdim];
        }

        f32x4 acc = (f32x4){0.f, 0.f, 0.f, 0.f};
        if (t > 0) {
            const unsigned short* hprev = hs + (size_t)(t - 1) * (Bdim * Hdim);
#pragma unroll
            for (int k16 = 0; k16 < 16; ++k16) {
                bf16x8 a = *(const bf16x8*)(hprev + arow + k16 * 32);
                bf16x8 b = *(const bf16x8*)&wlp[(k16 * 64 + l) * 8];
                acc = __builtin_amdgcn_mfma_f32_16x16x32_bf16(a, b, acc, 0, 0, 0);
            }
        }
        // C/D: col=lane&15 -> gate-row w*16+lr; row = quad*4+reg
#pragma unroll
        for (int r = 0; r < 4; ++r)
            g_lds[quad * 4 + r][w * 16 + lr] = acc[r];
        __syncthreads();

        // pointwise: gate g, local col phc -> g_lds column g*32 + phc.
        const float iv = g_lds[prow][phc]      + bf2f(epk[0]) + env[0];
        const float fv = g_lds[prow][32 + phc] + bf2f(epk[1]) + env[1];
        const float gv = g_lds[prow][64 + phc] + bf2f(epk[2]) + env[2];
        const float ov = g_lds[prow][96 + phc] + bf2f(epk[3]) + env[3];
        const float cn = sigmoid_f(fv) * c0 + sigmoid_f(iv) * tanh_f(gv);
        c0 = cn;
        const unsigned short hv = f2bf(sigmoid_f(ov) * tanh_f(cn));

        unsigned short* hsp = hs + (size_t)t * (Bdim * Hdim) + (size_t)brow * Hdim + h0 + phc;
        if (fast)
            *hsp = hv;                          // write-back, stays in XCD L2
        else
            __hip_atomic_store(hsp, hv, __ATOMIC_RELAXED, __HIP_MEMORY_SCOPE_AGENT);

        if (t != Sdim - 1) {
            if (fast) sync_fast(bar, bi, (unsigned)(t + 1));   // fast ctr starts at 0
            else      sync_agent(bar, bi, (unsigned)(t + 2));  // agent ctr holds init's 16
        }

#pragma unroll
        for (int g = 0; g < 4; ++g)
            epk[g] = epkn[g];
    }
}

// ---------------------------------------------------------------------------
// logits = hs[36096,512](bf16) * out_W^T(bf16) + out_b(fp32) -> fp32
// out[b][s][v], row m = s*256 + b.
// ---------------------------------------------------------------------------
__global__ __launch_bounds__(256) void gemm_logits(
    const unsigned short* __restrict__ A,
    const unsigned short* __restrict__ W,
    const float* __restrict__ bias,
    float* __restrict__ out)
{
    const int m0 = blockIdx.x * 128;
    const int n0 = blockIdx.y * 64;
    const int w    = threadIdx.x >> 6;
    const int l    = threadIdx.x & 63;
    const int lr   = l & 15;
    const int quad = l >> 4;

    const unsigned short* pa0 = A + (size_t)(m0 + w * 32 + lr) * Hdim + quad * 8;
    const unsigned short* pa1 = pa0 + (size_t)16 * Hdim;
    const unsigned short* pb[4];
#pragma unroll
    for (int nj = 0; nj < 4; ++nj) {
        int rb = n0 + nj * 16 + lr;
        rb = rb < Vdim ? rb : Vdim - 1;
        pb[nj] = W + (size_t)rb * Hdim + quad * 8;
    }

    f32x4 acc[2][4];
#pragma unroll
    for (int mi = 0; mi < 2; ++mi)
#pragma unroll
        for (int nj = 0; nj < 4; ++nj)
            acc[mi][nj] = (f32x4){0.f, 0.f, 0.f, 0.f};

    for (int k = 0; k < Hdim; k += 32) {
        bf16x8 a0 = *(const bf16x8*)(pa0 + k);
        bf16x8 a1 = *(const bf16x8*)(pa1 + k);
#pragma unroll
        for (int nj = 0; nj < 4; ++nj) {
            bf16x8 bb = *(const bf16x8*)(pb[nj] + k);
            acc[0][nj] = __builtin_amdgcn_mfma_f32_16x16x32_bf16(a0, bb, acc[0][nj], 0, 0, 0);
            acc[1][nj] = __builtin_amdgcn_mfma_f32_16x16x32_bf16(a1, bb, acc[1][nj], 0, 0, 0);
        }
    }

#pragma unroll
    for (int nj = 0; nj < 4; ++nj) {
        const int col = n0 + nj * 16 + lr;
        if (col >= Vdim) continue;
        const float bv = bias[col];
#pragma unroll
        for (int mi = 0; mi < 2; ++mi) {
            const int rowb = m0 + w * 32 + mi * 16 + quad * 4;
#pragma unroll
            for (int r = 0; r < 4; ++r) {
                const int row = rowb + r;            // row = s*256 + b
                const int s = row >> 8;
                const int b = row & 255;
                out[((size_t)b * Sdim + s) * Vdim + col] = acc[mi][nj][r] + bv;
            }
        }
    }
}

extern "C" void kernel_launch(void* const* d_in, const int* in_sizes, int n_in,
                              void* d_out, int out_size, void* d_ws, size_t ws_size,
                              hipStream_t stream) {
    const float* enc   = (const float*)d_in[0];
    const int*   tgt   = (const int*)d_in[1];
    const float* emb   = (const float*)d_in[2];
    const float* W_ih  = (const float*)d_in[3];
    const float* W_hh  = (const float*)d_in[4];
    const float* b_ih  = (const float*)d_in[5];
    const float* b_hh  = (const float*)d_in[6];
    // d_in[7..9]: attn_W / attn_b / v_w — dead code (softmax over 1 source pos)
    const float* out_W = (const float*)d_in[10];
    const float* out_b = (const float*)d_in[11];
    float* out = (float*)d_out;

    char* ws = (char*)d_ws;
    unsigned short* whh_bf   = (unsigned short*)ws;                     // 2,097,152 B
    unsigned short* outw_bf  = (unsigned short*)(ws + 2097152);         // 1,024,000 B
    unsigned short* emb_proj = (unsigned short*)(ws + 3121152);         // 4,096,000 B
    float*          enc_proj = (float*)(ws + 7217152);                  // 2,097,152 B
    unsigned short* hs       = (unsigned short*)(ws + 9314304);         // 36,962,304 B
    unsigned*       bar      = (unsigned*)(ws + 46276608);              // 4,096 B
    // total ws use = 46,280,704 B

    hipMemsetAsync(bar, 0, 4096, stream);   // barrier counters (re-poisoned each call)

    f32_to_bf16_4<<<dim3((262144 + 255) / 256), 256, 0, stream>>>(
        (const float4*)W_hh, (u16x4*)whh_bf, 262144);
    f32_to_bf16_4<<<dim3((128000 + 255) / 256), 256, 0, stream>>>(
        (const float4*)out_W, (u16x4*)outw_bf, 128000);

    // emb_proj = embedding @ W_ih[:, :E].T               (bf16, [1000,2048])
    gemm_bt_f32in<true><<<dim3(8, 32), 256, 0, stream>>>(
        emb, Edim, Vdim, W_ih, 2 * Edim, emb_proj, G4H, nullptr, nullptr, Edim);
    // enc_proj = encoder_output @ W_ih[:, E:].T + b_ih + b_hh   (fp32, [256,2048])
    gemm_bt_f32in<false><<<dim3(2, 32), 256, 0, stream>>>(
        enc, Edim, Bdim, W_ih + Edim, 2 * Edim, enc_proj, G4H, b_ih, b_hh, Edim);
    // weights-stationary scan: 256 blocks = 16 XCD-local tiles x 16 h-blocks
    lstm_scan<<<dim3(256), 512, 0, stream>>>(whh_bf, emb_proj, enc_proj, tgt, hs, bar);
    // logits = hs @ out_W.T + out_b   (fp32 out)
    gemm_logits<<<dim3(282, 16), 256, 0, stream>>>(hs, outw_bf, out_b, out);
}